// Round 3
// baseline (659.237 us; speedup 1.0000x reference)
//
#include <hip/hip_runtime.h>
#include <hip/hip_bf16.h>
#include <math.h>

#define NPOS 8192   // B*H*W = 8*32*32
#define DIMC 384
#define DIN 768
#define DST 16

__device__ __forceinline__ float b2f(unsigned short u) {
    return __uint_as_float(((unsigned int)u) << 16);
}
__device__ __forceinline__ unsigned short f2b(float f) {
    unsigned int u = __float_as_uint(f);
    u = (u + 0x7FFFu + ((u >> 16) & 1u)) >> 16;   // round-to-nearest-even
    return (unsigned short)u;
}

// ---------------------------------------------------------------- LayerNorm
// one wave per position; xn -> d_out (f32 scratch, dead after in_proj GEMM)
__global__ __launch_bounds__(256) void k_ln(const float* __restrict__ x,
        const float* __restrict__ g, const float* __restrict__ bta,
        float* __restrict__ xn, float* __restrict__ xg) {
    int wid = blockIdx.x * 4 + (threadIdx.x >> 6);
    int lane = threadIdx.x & 63;
    const float* xr = x + (size_t)wid * DIMC;
    float v[6];
    float s = 0.f, ss = 0.f;
#pragma unroll
    for (int i = 0; i < 6; i++) {
        v[i] = xr[lane + i * 64];
        s += v[i]; ss += v[i] * v[i];
    }
#pragma unroll
    for (int m = 32; m; m >>= 1) { s += __shfl_xor(s, m); ss += __shfl_xor(ss, m); }
    float mu = s * (1.f / DIMC);
    float var = ss * (1.f / DIMC) - mu * mu;
    float rstd = rsqrtf(var + 1e-5f);
    float* xnr = xn + (size_t)wid * DIMC;
    float sn = 0.f;
#pragma unroll
    for (int i = 0; i < 6; i++) {
        int c = lane + i * 64;
        float o = (v[i] - mu) * rstd * g[c] + bta[c];
        xnr[c] = o;
        sn += o;
    }
#pragma unroll
    for (int m = 32; m; m >>= 1) sn += __shfl_xor(sn, m);
    if (lane == 0) xg[wid] = sn * (1.f / DIMC);
}

// ---------------------------------------------------------------- direction
__global__ __launch_bounds__(256) void k_dir(const float* __restrict__ xg,
        const float* __restrict__ w1, const float* __restrict__ b1,
        const float* __restrict__ w2, const float* __restrict__ b2,
        int* __restrict__ vert) {
    __shared__ float sg[32][32];
    __shared__ float red[4][4];
    int b = blockIdx.x;
    int tid = threadIdx.x;
    for (int i = tid; i < 1024; i += 256) sg[i >> 5][i & 31] = xg[b * 1024 + i];
    __syncthreads();
    float ph = 0, pv = 0, pd = 0, pa = 0;
    const float iks = 1.f / 1.0625f;   // kernel_scale = 34/32 (antialias)
    for (int p = tid; p < 1024; p += 256) {
        int y = p >> 5, xq = p & 31;
        int xl = (xq >= 1) ? xq - 1 : 1;
        int xr2 = (xq <= 30) ? xq + 1 : 30;
        float sf = (y + 0.5f) * 1.0625f - 0.5f;
        int jlo = (int)ceilf(sf - 1.0625f); if (jlo < 0) jlo = 0;
        int jhi = (int)floorf(sf + 1.0625f); if (jhi > 33) jhi = 33;
        float acc = 0.f, wsum = 0.f;
        for (int j = jlo; j <= jhi; j++) {
            float wgt = 1.f - fabsf(sf - j) * iks;
            if (wgt <= 0.f) continue;
            int ry = (j >= 1) ? ((j <= 32) ? j - 1 : 30) : 1;
            acc += wgt * fabsf(sg[ry][xr2] - sg[ry][xl]);
            wsum += wgt;
        }
        float ghr = acc / wsum;
        int yu = (y >= 1) ? y - 1 : 1;
        int yd = (y <= 30) ? y + 1 : 30;
        float sfx = (xq + 0.5f) * 1.0625f - 0.5f;
        int ilo = (int)ceilf(sfx - 1.0625f); if (ilo < 0) ilo = 0;
        int ihi = (int)floorf(sfx + 1.0625f); if (ihi > 33) ihi = 33;
        float accv = 0.f, wsv = 0.f;
        for (int i = ilo; i <= ihi; i++) {
            float wgt = 1.f - fabsf(sfx - i) * iks;
            if (wgt <= 0.f) continue;
            int rx = (i >= 1) ? ((i <= 32) ? i - 1 : 30) : 1;
            accv += wgt * fabsf(sg[yd][rx] - sg[yu][rx]);
            wsv += wgt;
        }
        float gvr = accv / wsv;
        float gd = (ghr + gvr) * 0.5f;
        float ga = fabsf(ghr - gvr);
        float cw = ((y == 0 || y == 31) ? 2.f : 3.f) * ((xq == 0 || xq == 31) ? 2.f : 3.f);
        ph += ghr * cw; pv += gvr * cw; pd += gd * cw; pa += ga * cw;
    }
#pragma unroll
    for (int m = 32; m; m >>= 1) {
        ph += __shfl_xor(ph, m); pv += __shfl_xor(pv, m);
        pd += __shfl_xor(pd, m); pa += __shfl_xor(pa, m);
    }
    int wv = tid >> 6;
    if ((tid & 63) == 0) { red[wv][0] = ph; red[wv][1] = pv; red[wv][2] = pd; red[wv][3] = pa; }
    __syncthreads();
    if (tid == 0) {
        float sc[4];
        for (int k = 0; k < 4; k++)
            sc[k] = (red[0][k] + red[1][k] + red[2][k] + red[3][k]) * (1.f / 9216.f);
        float hdn[32];
        for (int j = 0; j < 32; j++) {
            float a = b1[j];
            for (int i = 0; i < 4; i++) a += sc[i] * w1[i * 32 + j];
            hdn[j] = a > 0.f ? a : 0.f;
        }
        float best = -1e30f; int bi = 0;
        for (int k = 0; k < 4; k++) {
            float a = b2[k];
            for (int j = 0; j < 32; j++) a += hdn[j] * w2[j * 4 + k];
            if (a > best) { best = a; bi = k; }
        }
        vert[b] = (bi == 1) ? 1 : 0;
    }
}

// ---------------------------------------------------------------- SGEMM
// 64x64 tile, BK=16, 4x4/thread, f32 accumulate.
// MODE 0: A f32 + vert-gather, C bf16            (in_proj; ldc=1536)
// MODE 1: A bf16, +bias +softplus, C bf16        (dt; ldc=1536)
// MODE 2: A bf16 (lda=1536), +resid(f32), C f32  (out_proj)
template <int MODE>
__global__ __launch_bounds__(256) void k_gemm(
        const void* __restrict__ Avp, const float* __restrict__ Wt,
        void* __restrict__ Cvp, const float* __restrict__ bias,
        const float* __restrict__ resid, const int* __restrict__ vert,
        int N, int K, int lda, int ldc) {
    __shared__ float As[16][64];
    __shared__ float Ws[16][64];
    int tid = threadIdx.x;
    int nb = N >> 6;
    int bx = blockIdx.x % nb;
    int by = blockIdx.x / nb;
    int row0 = by << 6, col0 = bx << 6;
    int tx = tid & 15, ty = tid >> 4;
    float c[4][4] = {};
    int mm = tid >> 2, kq = tid & 3;
    int arow = row0 + mm;
    size_t abase;
    if constexpr (MODE == 0) {
        int bb = arow >> 10, l = arow & 1023;
        int src = vert[bb] ? (((l & 31) << 5) | (l >> 5)) : l;
        abase = ((size_t)(bb << 10) + src) * lda;
    } else {
        abase = (size_t)arow * lda;
    }
    const float* Wp = Wt + (size_t)(tid >> 4) * N + col0 + ((tid & 15) << 2);
    for (int k0 = 0; k0 < K; k0 += 16) {
        float a0, a1, a2, a3;
        if constexpr (MODE == 0) {
            const float* Af = (const float*)Avp;
            float4 av = *(const float4*)(Af + abase + k0 + (kq << 2));
            a0 = av.x; a1 = av.y; a2 = av.z; a3 = av.w;
        } else {
            const unsigned short* Ab = (const unsigned short*)Avp;
            ushort4 av = *(const ushort4*)(Ab + abase + k0 + (kq << 2));
            a0 = b2f(av.x); a1 = b2f(av.y); a2 = b2f(av.z); a3 = b2f(av.w);
        }
        float4 wv = *(const float4*)(Wp + (size_t)k0 * N);
        As[(kq << 2) + 0][mm] = a0;
        As[(kq << 2) + 1][mm] = a1;
        As[(kq << 2) + 2][mm] = a2;
        As[(kq << 2) + 3][mm] = a3;
        *(float4*)&Ws[tid >> 4][(tid & 15) << 2] = wv;
        __syncthreads();
#pragma unroll
        for (int kk = 0; kk < 16; kk++) {
            float4 a = *(const float4*)&As[kk][ty << 2];
            float4 bv = *(const float4*)&Ws[kk][tx << 2];
            float ar[4] = {a.x, a.y, a.z, a.w};
            float br[4] = {bv.x, bv.y, bv.z, bv.w};
#pragma unroll
            for (int i = 0; i < 4; i++)
#pragma unroll
                for (int j = 0; j < 4; j++)
                    c[i][j] = fmaf(ar[i], br[j], c[i][j]);
        }
        __syncthreads();
    }
#pragma unroll
    for (int i = 0; i < 4; i++) {
        int r = row0 + (ty << 2) + i;
#pragma unroll
        for (int j = 0; j < 4; j++) {
            int cc = col0 + (tx << 2) + j;
            float v = c[i][j];
            if constexpr (MODE == 0) {
                ((unsigned short*)Cvp)[(size_t)r * ldc + cc] = f2b(v);
            } else if constexpr (MODE == 1) {
                v += bias[cc];
                v = fmaxf(v, 0.f) + log1pf(expf(-fabsf(v)));   // stable softplus
                ((unsigned short*)Cvp)[(size_t)r * ldc + cc] = f2b(v);
            } else {
                v += resid[(size_t)r * 384 + cc];
                ((float*)Cvp)[(size_t)r * ldc + cc] = v;
            }
        }
    }
}

// ---------------------------------------------------------------- depthwise conv3 + silu
// reads xc_raw (xzb cols<768, bf16), writes xc (bf16) into d_out
__global__ __launch_bounds__(256) void k_conv(const unsigned short* __restrict__ xzb,
        const float* __restrict__ cw, const float* __restrict__ cb,
        unsigned short* __restrict__ xcb) {
    int row = blockIdx.x;
    int l = row & 1023;
    const unsigned short* x0 = xzb + (size_t)row * 1536;
#pragma unroll
    for (int i = 0; i < 3; i++) {
        int d = threadIdx.x + i * 256;
        float v = cb[d] + cw[d * 3 + 1] * b2f(x0[d]);
        if (l > 0)    v += cw[d * 3 + 0] * b2f(x0[d - 1536]);
        if (l < 1023) v += cw[d * 3 + 2] * b2f(x0[d + 1536]);
        float sig = 1.f / (1.f + expf(-v));
        xcb[(size_t)row * 768 + d] = f2b(v * sig);
    }
}

// ---------------------------------------------------------------- x_proj (N=32), bf16 A, f32 out
__global__ __launch_bounds__(256) void k_xproj(const unsigned short* __restrict__ xcb,
        const float* __restrict__ xw, float* __restrict__ BC) {
    __shared__ float sx[8][768];
    int r0 = blockIdx.x * 8;
    int tid = threadIdx.x;
    for (int rr = 0; rr < 8; rr++)
#pragma unroll
        for (int i = 0; i < 3; i++)
            sx[rr][tid + i * 256] = b2f(xcb[(size_t)(r0 + rr) * 768 + tid + i * 256]);
    __syncthreads();
    int rr = tid >> 5, n = tid & 31;
    float acc = 0.f;
    for (int k = 0; k < 768; k++) acc = fmaf(sx[rr][k], xw[k * 32 + n], acc);
    BC[(size_t)(r0 + rr) * 32 + n] = acc;
}

// ---------------------------------------------------------------- fused selective scan
// reads delta (xzb cols<768), z (cols>=768), xc (d_out); writes y IN-PLACE over delta.
// In-place safe: delta[row,d] is read (all 16 n-lanes, lockstep wave) with a data
// dependency into the y value, and y[row,d] is the only same-address write.
#define SCAN_LOAD(dv, xv, zv, Bv, Cv, t0)                                 \
    _Pragma("unroll")                                                     \
    for (int j = 0; j < 8; j++) {                                         \
        size_t row = base + (size_t)(t0) + j;                             \
        dv[j] = b2f(xzb[row * 1536 + d]);                                 \
        xv[j] = b2f(xcb[row * 768 + d]);                                  \
        zv[j] = b2f(xzb[row * 1536 + 768 + d]);                           \
        Bv[j] = BC[row * 32 + n];                                         \
        Cv[j] = BC[row * 32 + 16 + n];                                    \
    }

#define SCAN_COMP(dv, xv, zv, Bv, Cv, t0)                                 \
    _Pragma("unroll")                                                     \
    for (int j = 0; j < 8; j++) {                                         \
        float dA = __expf(dv[j] * Av);                                    \
        h = fmaf(dA, h, dv[j] * xv[j] * Bv[j]);                           \
        float p = h * Cv[j];                                              \
        p += __shfl_xor(p, 1); p += __shfl_xor(p, 2);                     \
        p += __shfl_xor(p, 4); p += __shfl_xor(p, 8);                     \
        if (n == 0) {                                                     \
            float yv = p + Dv * xv[j];                                    \
            float zz = zv[j];                                             \
            float sig = 1.f / (1.f + __expf(-zz));                        \
            xzb[(base + (size_t)(t0) + j) * 1536 + d] = f2b(yv * zz * sig); \
        }                                                                 \
    }

__global__ __launch_bounds__(256) void k_scan(unsigned short* xzb,
        const unsigned short* __restrict__ xcb, const float* __restrict__ BC,
        const float* __restrict__ A_log, const float* __restrict__ Dp) {
    int blk = blockIdx.x;
    int b = blk / 48, dg = blk % 48;
    int tid = threadIdx.x;
    int dl = tid >> 4, n = tid & 15;
    int d = dg * 16 + dl;
    float Av = -expf(A_log[d * 16 + n]);
    float Dv = Dp[d];
    size_t base = (size_t)b * 1024;
    float h = 0.f;
    float dvA[8], xvA[8], zvA[8], BvA[8], CvA[8];
    float dvB[8], xvB[8], zvB[8], BvB[8], CvB[8];
    SCAN_LOAD(dvA, xvA, zvA, BvA, CvA, 0)
    for (int t0 = 0; t0 < 1024; t0 += 16) {
        SCAN_LOAD(dvB, xvB, zvB, BvB, CvB, t0 + 8)
        SCAN_COMP(dvA, xvA, zvA, BvA, CvA, t0)
        if (t0 + 16 < 1024) { SCAN_LOAD(dvA, xvA, zvA, BvA, CvA, t0 + 16) }
        SCAN_COMP(dvB, xvB, zvB, BvB, CvB, t0 + 8)
    }
}

// ---------------------------------------------------------------- launch
extern "C" void kernel_launch(void* const* d_in, const int* in_sizes, int n_in,
                              void* d_out, int out_size, void* d_ws, size_t ws_size,
                              hipStream_t stream) {
    const float* x    = (const float*)d_in[0];
    const float* ln_g = (const float*)d_in[1];
    const float* ln_b = (const float*)d_in[2];
    const float* mw1  = (const float*)d_in[3];
    const float* mb1  = (const float*)d_in[4];
    const float* mw2  = (const float*)d_in[5];
    const float* mb2  = (const float*)d_in[6];
    const float* inw  = (const float*)d_in[7];
    const float* cw   = (const float*)d_in[8];
    const float* cb   = (const float*)d_in[9];
    const float* xpw  = (const float*)d_in[10];
    const float* dtw  = (const float*)d_in[11];
    const float* dtb  = (const float*)d_in[12];
    const float* alog = (const float*)d_in[13];
    const float* Dp   = (const float*)d_in[14];
    const float* outw = (const float*)d_in[15];
    float* out = (float*)d_out;

    // ws footprint: 26.25 MB total (round 2 used 51.4 MB and still failed with a
    // corruption-scale error -> suspect ws_size ~= 48 MiB; stay well under).
    char* ws = (char*)d_ws;
    unsigned short* xzb = (unsigned short*)(ws);     // 8192*1536*2 = 25,165,824
                                                     //  cols<768: xc_raw -> delta -> y
                                                     //  cols>=768: z
    float* BCb = (float*)(ws + 25165824);            // 8192*32*4 = 1,048,576
    float* xg  = (float*)(ws + 26214400);            // 8192*4
    int*  vert = (int*)(ws + 26247168);              // 8*4

    // d_out: xn (f32) -> xc (bf16) -> final out (f32)
    float* xn = out;
    unsigned short* xcb = (unsigned short*)d_out;

    k_ln<<<2048, 256, 0, stream>>>(x, ln_g, ln_b, xn, xg);
    k_dir<<<8, 256, 0, stream>>>(xg, mw1, mb1, mw2, mb2, vert);
    // xz = seq @ in_proj_w  (M=8192,K=384,N=1536) -> bf16 into xzb
    k_gemm<0><<<(8192 / 64) * (1536 / 64), 256, 0, stream>>>(
        xn, inw, xzb, nullptr, nullptr, vert, 1536, 384, 384, 1536);
    // xc = silu(conv(xc_raw)) -> bf16 into d_out (xn dead)
    k_conv<<<8192, 256, 0, stream>>>(xzb, cw, cb, xcb);
    k_xproj<<<1024, 256, 0, stream>>>(xcb, xpw, BCb);
    // delta = softplus(xc @ dt_w + dt_b) -> bf16 over xc_raw (xzb cols<768)
    k_gemm<1><<<(8192 / 64) * (768 / 64), 256, 0, stream>>>(
        xcb, dtw, xzb, dtb, nullptr, nullptr, 768, 768, 768, 1536);
    // scan: y overwrites delta in-place (xzb cols<768)
    k_scan<<<384, 256, 0, stream>>>(xzb, xcb, BCb, alog, Dp);
    // out = x + (y @ out_proj_w); reads y from xzb (lda=1536), writes d_out (xc dead)
    k_gemm<2><<<(8192 / 64) * (384 / 64), 256, 0, stream>>>(
        xzb, outw, out, nullptr, x, nullptr, 384, 768, 1536, 384);
}

// Round 4
// 596.835 us; speedup vs baseline: 1.1046x; 1.1046x over previous
//
#include <hip/hip_runtime.h>
#include <hip/hip_bf16.h>
#include <math.h>

#define NPOS 8192   // B*H*W = 8*32*32
#define DIMC 384
#define DIN 768
#define DST 16

typedef unsigned int uint;

__device__ __forceinline__ float b2f(unsigned short u) {
    return __uint_as_float(((unsigned int)u) << 16);
}
__device__ __forceinline__ unsigned short f2b(float f) {
    unsigned int u = __float_as_uint(f);
    u = (u + 0x7FFFu + ((u >> 16) & 1u)) >> 16;   // round-to-nearest-even
    return (unsigned short)u;
}
__device__ __forceinline__ void ld_bf8(const unsigned short* p, float* o) {
    uint4 u = *(const uint4*)p;
    o[0] = b2f((unsigned short)(u.x & 0xffff));
    o[1] = b2f((unsigned short)(u.x >> 16));
    o[2] = b2f((unsigned short)(u.y & 0xffff));
    o[3] = b2f((unsigned short)(u.y >> 16));
    o[4] = b2f((unsigned short)(u.z & 0xffff));
    o[5] = b2f((unsigned short)(u.z >> 16));
    o[6] = b2f((unsigned short)(u.w & 0xffff));
    o[7] = b2f((unsigned short)(u.w >> 16));
}
__device__ __forceinline__ uint4 pack_bf8(const float* o) {
    uint4 p;
    p.x = (uint)f2b(o[0]) | ((uint)f2b(o[1]) << 16);
    p.y = (uint)f2b(o[2]) | ((uint)f2b(o[3]) << 16);
    p.z = (uint)f2b(o[4]) | ((uint)f2b(o[5]) << 16);
    p.w = (uint)f2b(o[6]) | ((uint)f2b(o[7]) << 16);
    return p;
}

// ---------------------------------------------------------------- LayerNorm
__global__ __launch_bounds__(256) void k_ln(const float* __restrict__ x,
        const float* __restrict__ g, const float* __restrict__ bta,
        float* __restrict__ xn, float* __restrict__ xg) {
    int wid = blockIdx.x * 4 + (threadIdx.x >> 6);
    int lane = threadIdx.x & 63;
    const float* xr = x + (size_t)wid * DIMC;
    float v[6];
    float s = 0.f, ss = 0.f;
#pragma unroll
    for (int i = 0; i < 6; i++) {
        v[i] = xr[lane + i * 64];
        s += v[i]; ss += v[i] * v[i];
    }
#pragma unroll
    for (int m = 32; m; m >>= 1) { s += __shfl_xor(s, m); ss += __shfl_xor(ss, m); }
    float mu = s * (1.f / DIMC);
    float var = ss * (1.f / DIMC) - mu * mu;
    float rstd = rsqrtf(var + 1e-5f);
    float* xnr = xn + (size_t)wid * DIMC;
    float sn = 0.f;
#pragma unroll
    for (int i = 0; i < 6; i++) {
        int c = lane + i * 64;
        float o = (v[i] - mu) * rstd * g[c] + bta[c];
        xnr[c] = o;
        sn += o;
    }
#pragma unroll
    for (int m = 32; m; m >>= 1) sn += __shfl_xor(sn, m);
    if (lane == 0) xg[wid] = sn * (1.f / DIMC);
}

// ---------------------------------------------------------------- direction
__global__ __launch_bounds__(256) void k_dir(const float* __restrict__ xg,
        const float* __restrict__ w1, const float* __restrict__ b1,
        const float* __restrict__ w2, const float* __restrict__ b2,
        int* __restrict__ vert) {
    __shared__ float sg[32][32];
    __shared__ float red[4][4];
    int b = blockIdx.x;
    int tid = threadIdx.x;
    for (int i = tid; i < 1024; i += 256) sg[i >> 5][i & 31] = xg[b * 1024 + i];
    __syncthreads();
    float ph = 0, pv = 0, pd = 0, pa = 0;
    const float iks = 1.f / 1.0625f;   // kernel_scale = 34/32 (antialias)
    for (int p = tid; p < 1024; p += 256) {
        int y = p >> 5, xq = p & 31;
        int xl = (xq >= 1) ? xq - 1 : 1;
        int xr2 = (xq <= 30) ? xq + 1 : 30;
        float sf = (y + 0.5f) * 1.0625f - 0.5f;
        int jlo = (int)ceilf(sf - 1.0625f); if (jlo < 0) jlo = 0;
        int jhi = (int)floorf(sf + 1.0625f); if (jhi > 33) jhi = 33;
        float acc = 0.f, wsum = 0.f;
        for (int j = jlo; j <= jhi; j++) {
            float wgt = 1.f - fabsf(sf - j) * iks;
            if (wgt <= 0.f) continue;
            int ry = (j >= 1) ? ((j <= 32) ? j - 1 : 30) : 1;
            acc += wgt * fabsf(sg[ry][xr2] - sg[ry][xl]);
            wsum += wgt;
        }
        float ghr = acc / wsum;
        int yu = (y >= 1) ? y - 1 : 1;
        int yd = (y <= 30) ? y + 1 : 30;
        float sfx = (xq + 0.5f) * 1.0625f - 0.5f;
        int ilo = (int)ceilf(sfx - 1.0625f); if (ilo < 0) ilo = 0;
        int ihi = (int)floorf(sfx + 1.0625f); if (ihi > 33) ihi = 33;
        float accv = 0.f, wsv = 0.f;
        for (int i = ilo; i <= ihi; i++) {
            float wgt = 1.f - fabsf(sfx - i) * iks;
            if (wgt <= 0.f) continue;
            int rx = (i >= 1) ? ((i <= 32) ? i - 1 : 30) : 1;
            accv += wgt * fabsf(sg[yd][rx] - sg[yu][rx]);
            wsv += wgt;
        }
        float gvr = accv / wsv;
        float gd = (ghr + gvr) * 0.5f;
        float ga = fabsf(ghr - gvr);
        float cw = ((y == 0 || y == 31) ? 2.f : 3.f) * ((xq == 0 || xq == 31) ? 2.f : 3.f);
        ph += ghr * cw; pv += gvr * cw; pd += gd * cw; pa += ga * cw;
    }
#pragma unroll
    for (int m = 32; m; m >>= 1) {
        ph += __shfl_xor(ph, m); pv += __shfl_xor(pv, m);
        pd += __shfl_xor(pd, m); pa += __shfl_xor(pa, m);
    }
    int wv = tid >> 6;
    if ((tid & 63) == 0) { red[wv][0] = ph; red[wv][1] = pv; red[wv][2] = pd; red[wv][3] = pa; }
    __syncthreads();
    if (tid == 0) {
        float sc[4];
        for (int k = 0; k < 4; k++)
            sc[k] = (red[0][k] + red[1][k] + red[2][k] + red[3][k]) * (1.f / 9216.f);
        float hdn[32];
        for (int j = 0; j < 32; j++) {
            float a = b1[j];
            for (int i = 0; i < 4; i++) a += sc[i] * w1[i * 32 + j];
            hdn[j] = a > 0.f ? a : 0.f;
        }
        float best = -1e30f; int bi = 0;
        for (int k = 0; k < 4; k++) {
            float a = b2[k];
            for (int j = 0; j < 32; j++) a += hdn[j] * w2[j * 4 + k];
            if (a > best) { best = a; bi = k; }
        }
        vert[b] = (bi == 1) ? 1 : 0;
    }
}

// ---------------------------------------------------------------- SGEMM
// 64x64 tile, BK=16, 4x4/thread, f32 accumulate. Channel-major intermediates.
// MODE 0: A f32 row-major + vert-gather; C bf16 TRANSPOSED [N][8192]  (in_proj)
// MODE 1: A bf16 TRANSPOSED [K][8192]; +bias+softplus; C bf16 TRANSPOSED (dt)
// MODE 2: A bf16 TRANSPOSED [K][8192]; +resid f32; C f32 row-major     (out_proj)
template <int MODE>
__global__ __launch_bounds__(256) void k_gemm(
        const void* __restrict__ Avp, const float* __restrict__ Wt,
        void* __restrict__ Cvp, const float* __restrict__ bias,
        const float* __restrict__ resid, const int* __restrict__ vert,
        int N, int K, int lda) {
    __shared__ float As[16][64];
    __shared__ float Ws[16][64];
    int tid = threadIdx.x;
    int nb = N >> 6;
    int bx = blockIdx.x % nb;
    int by = blockIdx.x / nb;
    int row0 = by << 6, col0 = bx << 6;
    int tx = tid & 15, ty = tid >> 4;
    float c[4][4] = {};
    size_t abase = 0;
    if constexpr (MODE == 0) {
        int mm = tid >> 2;
        int arow = row0 + mm;
        int bb = arow >> 10, l = arow & 1023;
        int src = vert[bb] ? (((l & 31) << 5) | (l >> 5)) : l;
        abase = ((size_t)(bb << 10) + src) * lda;
    }
    const float* Wp = Wt + (size_t)ty * N + col0 + (tx << 2);
    for (int k0 = 0; k0 < K; k0 += 16) {
        if constexpr (MODE == 0) {
            int mm = tid >> 2, kq = tid & 3;
            const float* Af = (const float*)Avp;
            float4 av = *(const float4*)(Af + abase + k0 + (kq << 2));
            As[(kq << 2) + 0][mm] = av.x;
            As[(kq << 2) + 1][mm] = av.y;
            As[(kq << 2) + 2][mm] = av.z;
            As[(kq << 2) + 3][mm] = av.w;
        } else {
            const unsigned short* At = (const unsigned short*)Avp;
            int kr = tid >> 4, rq = (tid & 15) << 2;
            ushort4 a4 = *(const ushort4*)(At + (size_t)(k0 + kr) * lda + row0 + rq);
            float4 f;
            f.x = b2f(a4.x); f.y = b2f(a4.y); f.z = b2f(a4.z); f.w = b2f(a4.w);
            *(float4*)&As[kr][rq] = f;
        }
        *(float4*)&Ws[ty][tx << 2] = *(const float4*)(Wp + (size_t)k0 * N);
        __syncthreads();
#pragma unroll
        for (int kk = 0; kk < 16; kk++) {
            float4 a = *(const float4*)&As[kk][ty << 2];
            float4 bv = *(const float4*)&Ws[kk][tx << 2];
            float ar[4] = {a.x, a.y, a.z, a.w};
            float br[4] = {bv.x, bv.y, bv.z, bv.w};
#pragma unroll
            for (int i = 0; i < 4; i++)
#pragma unroll
                for (int j = 0; j < 4; j++)
                    c[i][j] = fmaf(ar[i], br[j], c[i][j]);
        }
        __syncthreads();
    }
    int r = row0 + (ty << 2);
    if constexpr (MODE == 2) {
#pragma unroll
        for (int i = 0; i < 4; i++) {
            const float* rp = resid + (size_t)(r + i) * 384 + col0 + (tx << 2);
            float4 rv = *(const float4*)rp;
            float4 ov;
            ov.x = c[i][0] + rv.x; ov.y = c[i][1] + rv.y;
            ov.z = c[i][2] + rv.z; ov.w = c[i][3] + rv.w;
            *(float4*)((float*)Cvp + (size_t)(r + i) * 384 + col0 + (tx << 2)) = ov;
        }
    } else {
        unsigned short* CT = (unsigned short*)Cvp;
#pragma unroll
        for (int j = 0; j < 4; j++) {
            int cc = col0 + (tx << 2) + j;
            float v0 = c[0][j], v1 = c[1][j], v2 = c[2][j], v3 = c[3][j];
            if constexpr (MODE == 1) {
                float bz = bias[cc];
                v0 += bz; v1 += bz; v2 += bz; v3 += bz;
                v0 = fmaxf(v0, 0.f) + log1pf(expf(-fabsf(v0)));
                v1 = fmaxf(v1, 0.f) + log1pf(expf(-fabsf(v1)));
                v2 = fmaxf(v2, 0.f) + log1pf(expf(-fabsf(v2)));
                v3 = fmaxf(v3, 0.f) + log1pf(expf(-fabsf(v3)));
            }
            uint2 pk;
            pk.x = (uint)f2b(v0) | ((uint)f2b(v1) << 16);
            pk.y = (uint)f2b(v2) | ((uint)f2b(v3) << 16);
            *(uint2*)(CT + (size_t)cc * 8192 + r) = pk;
        }
    }
}

// ---------------------------------------------------------------- depthwise conv3 + silu
// channel-major: reads xz_T[d][t] (d<768), writes xc_T[d][t]. 16 timesteps/thread.
__global__ __launch_bounds__(256) void k_conv(const unsigned short* __restrict__ xzb,
        const float* __restrict__ cw, const float* __restrict__ cb,
        unsigned short* __restrict__ xcb) {
    int gc = blockIdx.x * 256 + threadIdx.x;   // 768 * 512
    int d = gc >> 9;
    int t0 = (gc & 511) << 4;
    const unsigned short* xr = xzb + (size_t)d * 8192;
    float xx[16];
    ld_bf8(xr + t0, xx);
    ld_bf8(xr + t0 + 8, xx + 8);
    int l0 = t0 & 1023;
    float xprev = (l0 != 0)    ? b2f(xr[t0 - 1])  : 0.f;
    float xnext = (l0 != 1008) ? b2f(xr[t0 + 16]) : 0.f;
    float w0 = cw[d * 3], w1 = cw[d * 3 + 1], w2 = cw[d * 3 + 2], bb = cb[d];
    float o[16];
#pragma unroll
    for (int j = 0; j < 16; j++) {
        float v = bb + w1 * xx[j];
        v += w0 * ((j == 0) ? xprev : xx[j - 1]);
        v += w2 * ((j == 15) ? xnext : xx[j + 1]);
        float sig = 1.f / (1.f + __expf(-v));
        o[j] = v * sig;
    }
    *(uint4*)(xcb + (size_t)d * 8192 + t0)     = pack_bf8(o);
    *(uint4*)(xcb + (size_t)d * 8192 + t0 + 8) = pack_bf8(o + 8);
}

// ---------------------------------------------------------------- x_proj
// BC_T[n][r] = sum_k xc_T[k][r] * xw[k][n];  block = 64 rows, LDS-staged k-tiles
__global__ __launch_bounds__(256) void k_xproj(const unsigned short* __restrict__ xcb,
        const float* __restrict__ xw, float* __restrict__ BC) {
    __shared__ unsigned short sx[32][64];
    int r0 = blockIdx.x * 64;
    int tid = threadIdx.x;
    int n = tid & 31, rg = tid >> 5;
    float acc[8] = {};
    for (int k0 = 0; k0 < 768; k0 += 32) {
        int kk = tid >> 3, r8 = (tid & 7) << 3;
        *(uint4*)&sx[kk][r8] = *(const uint4*)(xcb + (size_t)(k0 + kk) * 8192 + r0 + r8);
        __syncthreads();
#pragma unroll 8
        for (int k2 = 0; k2 < 32; k2++) {
            float w = xw[(k0 + k2) * 32 + n];
            float xb[8];
            ld_bf8(&sx[k2][rg << 3], xb);
#pragma unroll
            for (int j = 0; j < 8; j++) acc[j] = fmaf(xb[j], w, acc[j]);
        }
        __syncthreads();
    }
    float* dst = BC + (size_t)n * 8192 + r0 + (rg << 3);
    *(float4*)dst       = make_float4(acc[0], acc[1], acc[2], acc[3]);
    *(float4*)(dst + 4) = make_float4(acc[4], acc[5], acc[6], acc[7]);
}

// ---------------------------------------------------------------- fused selective scan
// channel-major streams; y overwrites delta in-place (read-before-write per chunk).
#define SCAN_LOAD(dv, xv, zv, Bv, Cv, t0)                \
    ld_bf8(dptr + (t0), dv);                             \
    ld_bf8(xptr + (t0), xv);                             \
    ld_bf8(zptr + (t0), zv);                             \
    *(float4*)&Bv[0] = *(const float4*)(Bp + (t0));      \
    *(float4*)&Bv[4] = *(const float4*)(Bp + (t0) + 4);  \
    *(float4*)&Cv[0] = *(const float4*)(Cp + (t0));      \
    *(float4*)&Cv[4] = *(const float4*)(Cp + (t0) + 4);

#define SCAN_COMP(dv, xv, zv, Bv, Cv, t0)                          \
    {                                                              \
        float yr[8];                                               \
        _Pragma("unroll")                                          \
        for (int j = 0; j < 8; j++) {                              \
            float dA = __expf(dv[j] * Av);                         \
            h = fmaf(dA, h, dv[j] * xv[j] * Bv[j]);                \
            float p = h * Cv[j];                                   \
            p += __shfl_xor(p, 1); p += __shfl_xor(p, 2);          \
            p += __shfl_xor(p, 4); p += __shfl_xor(p, 8);          \
            float zz = zv[j];                                      \
            float sig = 1.f / (1.f + __expf(-zz));                 \
            yr[j] = (p + Dv * xv[j]) * zz * sig;                   \
        }                                                          \
        if (n == 0) *(uint4*)(dptr + (t0)) = pack_bf8(yr);         \
    }

__global__ __launch_bounds__(256) void k_scan(unsigned short* xzb,
        const unsigned short* __restrict__ xcb, const float* __restrict__ BC,
        const float* __restrict__ A_log, const float* __restrict__ Dp) {
    int blk = blockIdx.x;
    int b = blk / 48, dg = blk % 48;
    int tid = threadIdx.x;
    int dl = tid >> 4, n = tid & 15;
    int d = dg * 16 + dl;
    float Av = -expf(A_log[d * 16 + n]);
    float Dv = Dp[d];
    size_t r0 = (size_t)b * 1024;
    unsigned short* dptr       = xzb + (size_t)d * 8192 + r0;          // delta -> y
    const unsigned short* zptr = xzb + (size_t)(768 + d) * 8192 + r0;  // z
    const unsigned short* xptr = xcb + (size_t)d * 8192 + r0;          // xc
    const float* Bp = BC + (size_t)n * 8192 + r0;
    const float* Cp = BC + (size_t)(16 + n) * 8192 + r0;
    float h = 0.f;
    float dvA[8], xvA[8], zvA[8], BvA[8], CvA[8];
    float dvB[8], xvB[8], zvB[8], BvB[8], CvB[8];
    SCAN_LOAD(dvA, xvA, zvA, BvA, CvA, 0)
    for (int t0 = 0; t0 < 1024; t0 += 16) {
        SCAN_LOAD(dvB, xvB, zvB, BvB, CvB, t0 + 8)
        SCAN_COMP(dvA, xvA, zvA, BvA, CvA, t0)
        if (t0 + 16 < 1024) { SCAN_LOAD(dvA, xvA, zvA, BvA, CvA, t0 + 16) }
        SCAN_COMP(dvB, xvB, zvB, BvB, CvB, t0 + 8)
    }
}

// ---------------------------------------------------------------- launch
extern "C" void kernel_launch(void* const* d_in, const int* in_sizes, int n_in,
                              void* d_out, int out_size, void* d_ws, size_t ws_size,
                              hipStream_t stream) {
    const float* x    = (const float*)d_in[0];
    const float* ln_g = (const float*)d_in[1];
    const float* ln_b = (const float*)d_in[2];
    const float* mw1  = (const float*)d_in[3];
    const float* mb1  = (const float*)d_in[4];
    const float* mw2  = (const float*)d_in[5];
    const float* mb2  = (const float*)d_in[6];
    const float* inw  = (const float*)d_in[7];
    const float* cw   = (const float*)d_in[8];
    const float* cb   = (const float*)d_in[9];
    const float* xpw  = (const float*)d_in[10];
    const float* dtw  = (const float*)d_in[11];
    const float* dtb  = (const float*)d_in[12];
    const float* alog = (const float*)d_in[13];
    const float* Dp   = (const float*)d_in[14];
    const float* outw = (const float*)d_in[15];
    float* out = (float*)d_out;

    // ws: 26.25 MB total (proven safe in round 3)
    char* ws = (char*)d_ws;
    unsigned short* xzb = (unsigned short*)(ws);     // xz_T [1536][8192] bf16
                                                     //  ch<768: xc_raw -> delta -> y
                                                     //  ch>=768: z
    float* BCb = (float*)(ws + 25165824);            // BC_T [32][8192] f32
    float* xg  = (float*)(ws + 26214400);            // 8192*4
    int*  vert = (int*)(ws + 26247168);              // 8*4

    float* xn = out;                                 // d_out: xn(f32) -> xc_T(bf16) -> out(f32)
    unsigned short* xcb = (unsigned short*)d_out;

    k_ln<<<2048, 256, 0, stream>>>(x, ln_g, ln_b, xn, xg);
    k_dir<<<8, 256, 0, stream>>>(xg, mw1, mb1, mw2, mb2, vert);
    // xz_T = (seq @ in_proj_w)^T : M=8192,K=384,N=1536, C transposed
    k_gemm<0><<<128 * 24, 256, 0, stream>>>(
        xn, inw, xzb, nullptr, nullptr, vert, 1536, 384, 384);
    // xc_T = silu(conv(xc_raw_T))
    k_conv<<<1536, 256, 0, stream>>>(xzb, cw, cb, xcb);
    // BC_T = (xc @ x_proj_w)^T
    k_xproj<<<128, 256, 0, stream>>>(xcb, xpw, BCb);
    // delta_T = softplus(xc @ dt_w + dt_b)^T over xz_T ch<768
    k_gemm<1><<<128 * 12, 256, 0, stream>>>(
        xcb, dtw, xzb, dtb, nullptr, nullptr, 768, 768, 8192);
    // scan: y_T overwrites delta_T in-place
    k_scan<<<384, 256, 0, stream>>>(xzb, xcb, BCb, alog, Dp);
    // out = x + y @ out_proj_w : A = y_T (lda=8192), C row-major f32
    k_gemm<2><<<128 * 6, 256, 0, stream>>>(
        xzb, outw, out, nullptr, x, nullptr, 384, 768, 8192);
}

// Round 5
// 596.356 us; speedup vs baseline: 1.1054x; 1.0008x over previous
//
#include <hip/hip_runtime.h>
#include <hip/hip_bf16.h>
#include <math.h>

#define NPOS 8192   // B*H*W = 8*32*32
#define DIMC 384
#define DIN 768
#define DST 16
#define CHUNK 128
#define NCH 8       // 1024 / CHUNK

typedef unsigned int uint;

__device__ __forceinline__ float b2f(unsigned short u) {
    return __uint_as_float(((unsigned int)u) << 16);
}
__device__ __forceinline__ unsigned short f2b(float f) {
    unsigned int u = __float_as_uint(f);
    u = (u + 0x7FFFu + ((u >> 16) & 1u)) >> 16;   // round-to-nearest-even
    return (unsigned short)u;
}
__device__ __forceinline__ void ld_bf8(const unsigned short* p, float* o) {
    uint4 u = *(const uint4*)p;
    o[0] = b2f((unsigned short)(u.x & 0xffff));
    o[1] = b2f((unsigned short)(u.x >> 16));
    o[2] = b2f((unsigned short)(u.y & 0xffff));
    o[3] = b2f((unsigned short)(u.y >> 16));
    o[4] = b2f((unsigned short)(u.z & 0xffff));
    o[5] = b2f((unsigned short)(u.z >> 16));
    o[6] = b2f((unsigned short)(u.w & 0xffff));
    o[7] = b2f((unsigned short)(u.w >> 16));
}
__device__ __forceinline__ uint4 pack_bf8(const float* o) {
    uint4 p;
    p.x = (uint)f2b(o[0]) | ((uint)f2b(o[1]) << 16);
    p.y = (uint)f2b(o[2]) | ((uint)f2b(o[3]) << 16);
    p.z = (uint)f2b(o[4]) | ((uint)f2b(o[5]) << 16);
    p.w = (uint)f2b(o[6]) | ((uint)f2b(o[7]) << 16);
    return p;
}

// ---------------------------------------------------------------- LayerNorm
__global__ __launch_bounds__(256) void k_ln(const float* __restrict__ x,
        const float* __restrict__ g, const float* __restrict__ bta,
        float* __restrict__ xn, float* __restrict__ xg) {
    int wid = blockIdx.x * 4 + (threadIdx.x >> 6);
    int lane = threadIdx.x & 63;
    const float* xr = x + (size_t)wid * DIMC;
    float v[6];
    float s = 0.f, ss = 0.f;
#pragma unroll
    for (int i = 0; i < 6; i++) {
        v[i] = xr[lane + i * 64];
        s += v[i]; ss += v[i] * v[i];
    }
#pragma unroll
    for (int m = 32; m; m >>= 1) { s += __shfl_xor(s, m); ss += __shfl_xor(ss, m); }
    float mu = s * (1.f / DIMC);
    float var = ss * (1.f / DIMC) - mu * mu;
    float rstd = rsqrtf(var + 1e-5f);
    float* xnr = xn + (size_t)wid * DIMC;
    float sn = 0.f;
#pragma unroll
    for (int i = 0; i < 6; i++) {
        int c = lane + i * 64;
        float o = (v[i] - mu) * rstd * g[c] + bta[c];
        xnr[c] = o;
        sn += o;
    }
#pragma unroll
    for (int m = 32; m; m >>= 1) sn += __shfl_xor(sn, m);
    if (lane == 0) xg[wid] = sn * (1.f / DIMC);
}

// ---------------------------------------------------------------- direction
__global__ __launch_bounds__(256) void k_dir(const float* __restrict__ xg,
        const float* __restrict__ w1, const float* __restrict__ b1,
        const float* __restrict__ w2, const float* __restrict__ b2,
        int* __restrict__ vert) {
    __shared__ float sg[32][32];
    __shared__ float red[4][4];
    int b = blockIdx.x;
    int tid = threadIdx.x;
    for (int i = tid; i < 1024; i += 256) sg[i >> 5][i & 31] = xg[b * 1024 + i];
    __syncthreads();
    float ph = 0, pv = 0, pd = 0, pa = 0;
    const float iks = 1.f / 1.0625f;   // kernel_scale = 34/32 (antialias)
    for (int p = tid; p < 1024; p += 256) {
        int y = p >> 5, xq = p & 31;
        int xl = (xq >= 1) ? xq - 1 : 1;
        int xr2 = (xq <= 30) ? xq + 1 : 30;
        float sf = (y + 0.5f) * 1.0625f - 0.5f;
        int jlo = (int)ceilf(sf - 1.0625f); if (jlo < 0) jlo = 0;
        int jhi = (int)floorf(sf + 1.0625f); if (jhi > 33) jhi = 33;
        float acc = 0.f, wsum = 0.f;
        for (int j = jlo; j <= jhi; j++) {
            float wgt = 1.f - fabsf(sf - j) * iks;
            if (wgt <= 0.f) continue;
            int ry = (j >= 1) ? ((j <= 32) ? j - 1 : 30) : 1;
            acc += wgt * fabsf(sg[ry][xr2] - sg[ry][xl]);
            wsum += wgt;
        }
        float ghr = acc / wsum;
        int yu = (y >= 1) ? y - 1 : 1;
        int yd = (y <= 30) ? y + 1 : 30;
        float sfx = (xq + 0.5f) * 1.0625f - 0.5f;
        int ilo = (int)ceilf(sfx - 1.0625f); if (ilo < 0) ilo = 0;
        int ihi = (int)floorf(sfx + 1.0625f); if (ihi > 33) ihi = 33;
        float accv = 0.f, wsv = 0.f;
        for (int i = ilo; i <= ihi; i++) {
            float wgt = 1.f - fabsf(sfx - i) * iks;
            if (wgt <= 0.f) continue;
            int rx = (i >= 1) ? ((i <= 32) ? i - 1 : 30) : 1;
            accv += wgt * fabsf(sg[yd][rx] - sg[yu][rx]);
            wsv += wgt;
        }
        float gvr = accv / wsv;
        float gd = (ghr + gvr) * 0.5f;
        float ga = fabsf(ghr - gvr);
        float cw = ((y == 0 || y == 31) ? 2.f : 3.f) * ((xq == 0 || xq == 31) ? 2.f : 3.f);
        ph += ghr * cw; pv += gvr * cw; pd += gd * cw; pa += ga * cw;
    }
#pragma unroll
    for (int m = 32; m; m >>= 1) {
        ph += __shfl_xor(ph, m); pv += __shfl_xor(pv, m);
        pd += __shfl_xor(pd, m); pa += __shfl_xor(pa, m);
    }
    int wv = tid >> 6;
    if ((tid & 63) == 0) { red[wv][0] = ph; red[wv][1] = pv; red[wv][2] = pd; red[wv][3] = pa; }
    __syncthreads();
    if (tid == 0) {
        float sc[4];
        for (int k = 0; k < 4; k++)
            sc[k] = (red[0][k] + red[1][k] + red[2][k] + red[3][k]) * (1.f / 9216.f);
        float hdn[32];
        for (int j = 0; j < 32; j++) {
            float a = b1[j];
            for (int i = 0; i < 4; i++) a += sc[i] * w1[i * 32 + j];
            hdn[j] = a > 0.f ? a : 0.f;
        }
        float best = -1e30f; int bi = 0;
        for (int k = 0; k < 4; k++) {
            float a = b2[k];
            for (int j = 0; j < 32; j++) a += hdn[j] * w2[j * 4 + k];
            if (a > best) { best = a; bi = k; }
        }
        vert[b] = (bi == 1) ? 1 : 0;
    }
}

// ---------------------------------------------------------------- SGEMM
// 64x64 tile, BK=16, 4x4/thread, f32 accumulate. Channel-major intermediates.
// MODE 0: A f32 row-major + vert-gather; C bf16 TRANSPOSED [N][8192]  (in_proj)
// MODE 1: A bf16 TRANSPOSED [K][8192]; +bias+softplus; C bf16 TRANSPOSED (dt)
// MODE 2: A bf16 TRANSPOSED [K][8192]; +resid f32; C f32 row-major     (out_proj)
template <int MODE>
__global__ __launch_bounds__(256) void k_gemm(
        const void* __restrict__ Avp, const float* __restrict__ Wt,
        void* __restrict__ Cvp, const float* __restrict__ bias,
        const float* __restrict__ resid, const int* __restrict__ vert,
        int N, int K, int lda) {
    __shared__ float As[16][64];
    __shared__ float Ws[16][64];
    int tid = threadIdx.x;
    int nb = N >> 6;
    int bx = blockIdx.x % nb;
    int by = blockIdx.x / nb;
    int row0 = by << 6, col0 = bx << 6;
    int tx = tid & 15, ty = tid >> 4;
    float c[4][4] = {};
    size_t abase = 0;
    if constexpr (MODE == 0) {
        int mm = tid >> 2;
        int arow = row0 + mm;
        int bb = arow >> 10, l = arow & 1023;
        int src = vert[bb] ? (((l & 31) << 5) | (l >> 5)) : l;
        abase = ((size_t)(bb << 10) + src) * lda;
    }
    const float* Wp = Wt + (size_t)ty * N + col0 + (tx << 2);
    for (int k0 = 0; k0 < K; k0 += 16) {
        if constexpr (MODE == 0) {
            int mm = tid >> 2, kq = tid & 3;
            const float* Af = (const float*)Avp;
            float4 av = *(const float4*)(Af + abase + k0 + (kq << 2));
            As[(kq << 2) + 0][mm] = av.x;
            As[(kq << 2) + 1][mm] = av.y;
            As[(kq << 2) + 2][mm] = av.z;
            As[(kq << 2) + 3][mm] = av.w;
        } else {
            const unsigned short* At = (const unsigned short*)Avp;
            int kr = tid >> 4, rq = (tid & 15) << 2;
            ushort4 a4 = *(const ushort4*)(At + (size_t)(k0 + kr) * lda + row0 + rq);
            float4 f;
            f.x = b2f(a4.x); f.y = b2f(a4.y); f.z = b2f(a4.z); f.w = b2f(a4.w);
            *(float4*)&As[kr][rq] = f;
        }
        *(float4*)&Ws[ty][tx << 2] = *(const float4*)(Wp + (size_t)k0 * N);
        __syncthreads();
#pragma unroll
        for (int kk = 0; kk < 16; kk++) {
            float4 a = *(const float4*)&As[kk][ty << 2];
            float4 bv = *(const float4*)&Ws[kk][tx << 2];
            float ar[4] = {a.x, a.y, a.z, a.w};
            float br[4] = {bv.x, bv.y, bv.z, bv.w};
#pragma unroll
            for (int i = 0; i < 4; i++)
#pragma unroll
                for (int j = 0; j < 4; j++)
                    c[i][j] = fmaf(ar[i], br[j], c[i][j]);
        }
        __syncthreads();
    }
    int r = row0 + (ty << 2);
    if constexpr (MODE == 2) {
#pragma unroll
        for (int i = 0; i < 4; i++) {
            const float* rp = resid + (size_t)(r + i) * 384 + col0 + (tx << 2);
            float4 rv = *(const float4*)rp;
            float4 ov;
            ov.x = c[i][0] + rv.x; ov.y = c[i][1] + rv.y;
            ov.z = c[i][2] + rv.z; ov.w = c[i][3] + rv.w;
            *(float4*)((float*)Cvp + (size_t)(r + i) * 384 + col0 + (tx << 2)) = ov;
        }
    } else {
        unsigned short* CT = (unsigned short*)Cvp;
#pragma unroll
        for (int j = 0; j < 4; j++) {
            int cc = col0 + (tx << 2) + j;
            float v0 = c[0][j], v1 = c[1][j], v2 = c[2][j], v3 = c[3][j];
            if constexpr (MODE == 1) {
                float bz = bias[cc];
                v0 += bz; v1 += bz; v2 += bz; v3 += bz;
                v0 = fmaxf(v0, 0.f) + log1pf(expf(-fabsf(v0)));
                v1 = fmaxf(v1, 0.f) + log1pf(expf(-fabsf(v1)));
                v2 = fmaxf(v2, 0.f) + log1pf(expf(-fabsf(v2)));
                v3 = fmaxf(v3, 0.f) + log1pf(expf(-fabsf(v3)));
            }
            uint2 pk;
            pk.x = (uint)f2b(v0) | ((uint)f2b(v1) << 16);
            pk.y = (uint)f2b(v2) | ((uint)f2b(v3) << 16);
            *(uint2*)(CT + (size_t)cc * 8192 + r) = pk;
        }
    }
}

// ---------------------------------------------------------------- depthwise conv3 + silu
__global__ __launch_bounds__(256) void k_conv(const unsigned short* __restrict__ xzb,
        const float* __restrict__ cw, const float* __restrict__ cb,
        unsigned short* __restrict__ xcb) {
    int gc = blockIdx.x * 256 + threadIdx.x;   // 768 * 512
    int d = gc >> 9;
    int t0 = (gc & 511) << 4;
    const unsigned short* xr = xzb + (size_t)d * 8192;
    float xx[16];
    ld_bf8(xr + t0, xx);
    ld_bf8(xr + t0 + 8, xx + 8);
    int l0 = t0 & 1023;
    float xprev = (l0 != 0)    ? b2f(xr[t0 - 1])  : 0.f;
    float xnext = (l0 != 1008) ? b2f(xr[t0 + 16]) : 0.f;
    float w0 = cw[d * 3], w1 = cw[d * 3 + 1], w2 = cw[d * 3 + 2], bb = cb[d];
    float o[16];
#pragma unroll
    for (int j = 0; j < 16; j++) {
        float v = bb + w1 * xx[j];
        v += w0 * ((j == 0) ? xprev : xx[j - 1]);
        v += w2 * ((j == 15) ? xnext : xx[j + 1]);
        float sig = 1.f / (1.f + __expf(-v));
        o[j] = v * sig;
    }
    *(uint4*)(xcb + (size_t)d * 8192 + t0)     = pack_bf8(o);
    *(uint4*)(xcb + (size_t)d * 8192 + t0 + 8) = pack_bf8(o + 8);
}

// ---------------------------------------------------------------- x_proj
__global__ __launch_bounds__(256) void k_xproj(const unsigned short* __restrict__ xcb,
        const float* __restrict__ xw, float* __restrict__ BC) {
    __shared__ unsigned short sx[32][64];
    int r0 = blockIdx.x * 64;
    int tid = threadIdx.x;
    int n = tid & 31, rg = tid >> 5;
    float acc[8] = {};
    for (int k0 = 0; k0 < 768; k0 += 32) {
        int kk = tid >> 3, r8 = (tid & 7) << 3;
        *(uint4*)&sx[kk][r8] = *(const uint4*)(xcb + (size_t)(k0 + kk) * 8192 + r0 + r8);
        __syncthreads();
#pragma unroll 8
        for (int k2 = 0; k2 < 32; k2++) {
            float w = xw[(k0 + k2) * 32 + n];
            float xb[8];
            ld_bf8(&sx[k2][rg << 3], xb);
#pragma unroll
            for (int j = 0; j < 8; j++) acc[j] = fmaf(xb[j], w, acc[j]);
        }
        __syncthreads();
    }
    float* dst = BC + (size_t)n * 8192 + r0 + (rg << 3);
    *(float4*)dst       = make_float4(acc[0], acc[1], acc[2], acc[3]);
    *(float4*)(dst + 4) = make_float4(acc[4], acc[5], acc[6], acc[7]);
}

// ---------------------------------------------------------------- chunked scan
// Pass 1: per-chunk local scan from h=0 -> G[b][c][d][n] (bf16), sumd[b][c][d]
__global__ __launch_bounds__(256) void k_scan1(const unsigned short* __restrict__ xzb,
        const unsigned short* __restrict__ xcb, const float* __restrict__ BC,
        const float* __restrict__ A_log,
        unsigned short* __restrict__ G, float* __restrict__ sumd) {
    int blk = blockIdx.x;              // 8b * NCH * 48dg
    int dg = blk % 48;
    int c  = (blk / 48) % NCH;
    int b  = blk / (48 * NCH);
    int tid = threadIdx.x;
    int dl = tid >> 4, n = tid & 15;
    int d = dg * 16 + dl;
    float Av = -expf(A_log[d * 16 + n]);
    size_t r0 = (size_t)b * 1024 + c * CHUNK;
    const unsigned short* dptr = xzb + (size_t)d * 8192 + r0;
    const unsigned short* xptr = xcb + (size_t)d * 8192 + r0;
    const float* Bp = BC + (size_t)n * 8192 + r0;
    float h = 0.f, sd = 0.f;
    for (int t0 = 0; t0 < CHUNK; t0 += 8) {
        float dv[8], xv[8], Bv[8];
        ld_bf8(dptr + t0, dv);
        ld_bf8(xptr + t0, xv);
        *(float4*)&Bv[0] = *(const float4*)(Bp + t0);
        *(float4*)&Bv[4] = *(const float4*)(Bp + t0 + 4);
#pragma unroll
        for (int j = 0; j < 8; j++) {
            float dA = __expf(dv[j] * Av);
            h = fmaf(dA, h, dv[j] * xv[j] * Bv[j]);
            sd += dv[j];
        }
    }
    size_t gi = (((size_t)(b * NCH + c)) * 768 + d) * 16 + n;
    G[gi] = f2b(h);
    if (n == 0) sumd[(size_t)(b * NCH + c) * 768 + d] = sd;
}

// Pass 2: sequential carry across chunks; G[b][c][d][n] := carry-IN state of chunk c
__global__ __launch_bounds__(256) void k_scan2(unsigned short* __restrict__ G,
        const float* __restrict__ sumd, const float* __restrict__ A_log) {
    int blk = blockIdx.x;              // 8b * 48dg
    int dg = blk % 48, b = blk / 48;
    int tid = threadIdx.x;
    int dl = tid >> 4, n = tid & 15;
    int d = dg * 16 + dl;
    float Av = -expf(A_log[d * 16 + n]);
    float H = 0.f;
#pragma unroll
    for (int c = 0; c < NCH; c++) {
        size_t gi = (((size_t)(b * NCH + c)) * 768 + d) * 16 + n;
        float Gv = b2f(G[gi]);
        float P = __expf(Av * sumd[(size_t)(b * NCH + c) * 768 + d]);
        G[gi] = f2b(H);                // carry-in for chunk c
        H = fmaf(P, H, Gv);
    }
}

// Pass 3: full scan per chunk seeded with carry-in; y overwrites delta in-place.
#define SCAN_LOAD(dv, xv, zv, Bv, Cv, t0)                \
    ld_bf8(dptr + (t0), dv);                             \
    ld_bf8(xptr + (t0), xv);                             \
    ld_bf8(zptr + (t0), zv);                             \
    *(float4*)&Bv[0] = *(const float4*)(Bp + (t0));      \
    *(float4*)&Bv[4] = *(const float4*)(Bp + (t0) + 4);  \
    *(float4*)&Cv[0] = *(const float4*)(Cp + (t0));      \
    *(float4*)&Cv[4] = *(const float4*)(Cp + (t0) + 4);

#define SCAN_COMP(dv, xv, zv, Bv, Cv, t0)                          \
    {                                                              \
        float yr[8];                                               \
        _Pragma("unroll")                                          \
        for (int j = 0; j < 8; j++) {                              \
            float dA = __expf(dv[j] * Av);                         \
            h = fmaf(dA, h, dv[j] * xv[j] * Bv[j]);                \
            float p = h * Cv[j];                                   \
            p += __shfl_xor(p, 1); p += __shfl_xor(p, 2);          \
            p += __shfl_xor(p, 4); p += __shfl_xor(p, 8);          \
            float zz = zv[j];                                      \
            float sig = 1.f / (1.f + __expf(-zz));                 \
            yr[j] = (p + Dv * xv[j]) * zz * sig;                   \
        }                                                          \
        if (n == 0) *(uint4*)(dptr + (t0)) = pack_bf8(yr);         \
    }

__global__ __launch_bounds__(256) void k_scan3(unsigned short* xzb,
        const unsigned short* __restrict__ xcb, const float* __restrict__ BC,
        const float* __restrict__ A_log, const float* __restrict__ Dp,
        const unsigned short* __restrict__ G) {
    int blk = blockIdx.x;              // 8b * NCH * 48dg
    int dg = blk % 48;
    int c  = (blk / 48) % NCH;
    int b  = blk / (48 * NCH);
    int tid = threadIdx.x;
    int dl = tid >> 4, n = tid & 15;
    int d = dg * 16 + dl;
    float Av = -expf(A_log[d * 16 + n]);
    float Dv = Dp[d];
    size_t r0 = (size_t)b * 1024 + c * CHUNK;
    unsigned short* dptr       = xzb + (size_t)d * 8192 + r0;          // delta -> y
    const unsigned short* zptr = xzb + (size_t)(768 + d) * 8192 + r0;  // z
    const unsigned short* xptr = xcb + (size_t)d * 8192 + r0;          // xc
    const float* Bp = BC + (size_t)n * 8192 + r0;
    const float* Cp = BC + (size_t)(16 + n) * 8192 + r0;
    float h = b2f(G[(((size_t)(b * NCH + c)) * 768 + d) * 16 + n]);
    float dvA[8], xvA[8], zvA[8], BvA[8], CvA[8];
    float dvB[8], xvB[8], zvB[8], BvB[8], CvB[8];
    SCAN_LOAD(dvA, xvA, zvA, BvA, CvA, 0)
    for (int t0 = 0; t0 < CHUNK; t0 += 16) {
        SCAN_LOAD(dvB, xvB, zvB, BvB, CvB, t0 + 8)
        SCAN_COMP(dvA, xvA, zvA, BvA, CvA, t0)
        if (t0 + 16 < CHUNK) { SCAN_LOAD(dvA, xvA, zvA, BvA, CvA, t0 + 16) }
        SCAN_COMP(dvB, xvB, zvB, BvB, CvB, t0 + 8)
    }
}

// ---------------------------------------------------------------- launch
extern "C" void kernel_launch(void* const* d_in, const int* in_sizes, int n_in,
                              void* d_out, int out_size, void* d_ws, size_t ws_size,
                              hipStream_t stream) {
    const float* x    = (const float*)d_in[0];
    const float* ln_g = (const float*)d_in[1];
    const float* ln_b = (const float*)d_in[2];
    const float* mw1  = (const float*)d_in[3];
    const float* mb1  = (const float*)d_in[4];
    const float* mw2  = (const float*)d_in[5];
    const float* mb2  = (const float*)d_in[6];
    const float* inw  = (const float*)d_in[7];
    const float* cw   = (const float*)d_in[8];
    const float* cb   = (const float*)d_in[9];
    const float* xpw  = (const float*)d_in[10];
    const float* dtw  = (const float*)d_in[11];
    const float* dtb  = (const float*)d_in[12];
    const float* alog = (const float*)d_in[13];
    const float* Dp   = (const float*)d_in[14];
    const float* outw = (const float*)d_in[15];
    float* out = (float*)d_out;

    // ws: 28.1 MB total (26.25 proven safe; +1.8 MB for chunk-scan G/sumd)
    char* ws = (char*)d_ws;
    unsigned short* xzb = (unsigned short*)(ws);     // xz_T [1536][8192] bf16
    float* BCb = (float*)(ws + 25165824);            // BC_T [32][8192] f32
    float* xg  = (float*)(ws + 26214400);            // 8192*4
    int*  vert = (int*)(ws + 26247168);              // 8*4
    unsigned short* G = (unsigned short*)(ws + 26248192);  // [8][NCH][768][16] bf16 = 1,572,864
    float* sumd = (float*)(ws + 27821056);           // [8][NCH][768] f32 = 196,608  (ends 28,017,664)

    float* xn = out;                                 // d_out: xn(f32) -> xc_T(bf16) -> out(f32)
    unsigned short* xcb = (unsigned short*)d_out;

    k_ln<<<2048, 256, 0, stream>>>(x, ln_g, ln_b, xn, xg);
    k_dir<<<8, 256, 0, stream>>>(xg, mw1, mb1, mw2, mb2, vert);
    k_gemm<0><<<128 * 24, 256, 0, stream>>>(
        xn, inw, xzb, nullptr, nullptr, vert, 1536, 384, 384);
    k_conv<<<1536, 256, 0, stream>>>(xzb, cw, cb, xcb);
    k_xproj<<<128, 256, 0, stream>>>(xcb, xpw, BCb);
    k_gemm<1><<<128 * 12, 256, 0, stream>>>(
        xcb, dtw, xzb, dtb, nullptr, nullptr, 768, 768, 8192);
    k_scan1<<<8 * NCH * 48, 256, 0, stream>>>(xzb, xcb, BCb, alog, G, sumd);
    k_scan2<<<8 * 48, 256, 0, stream>>>(G, sumd, alog);
    k_scan3<<<8 * NCH * 48, 256, 0, stream>>>(xzb, xcb, BCb, alog, Dp, G);
    k_gemm<2><<<128 * 6, 256, 0, stream>>>(
        xzb, outw, out, nullptr, x, nullptr, 384, 768, 8192);
}

// Round 6
// 343.245 us; speedup vs baseline: 1.9206x; 1.7374x over previous
//
#include <hip/hip_runtime.h>
#include <hip/hip_bf16.h>
#include <math.h>

#define NPOS 8192   // B*H*W = 8*32*32
#define DIMC 384
#define DIN 768
#define DST 16
#define CHUNK 128
#define NCH 8       // 1024 / CHUNK

typedef unsigned int uint;
typedef __attribute__((ext_vector_type(8))) short bf16x8;
typedef __attribute__((ext_vector_type(4))) float f32x4;

__device__ __forceinline__ float b2f(unsigned short u) {
    return __uint_as_float(((unsigned int)u) << 16);
}
__device__ __forceinline__ unsigned short f2b(float f) {
    unsigned int u = __float_as_uint(f);
    u = (u + 0x7FFFu + ((u >> 16) & 1u)) >> 16;   // round-to-nearest-even
    return (unsigned short)u;
}
__device__ __forceinline__ void ld_bf8(const unsigned short* p, float* o) {
    uint4 u = *(const uint4*)p;
    o[0] = b2f((unsigned short)(u.x & 0xffff));
    o[1] = b2f((unsigned short)(u.x >> 16));
    o[2] = b2f((unsigned short)(u.y & 0xffff));
    o[3] = b2f((unsigned short)(u.y >> 16));
    o[4] = b2f((unsigned short)(u.z & 0xffff));
    o[5] = b2f((unsigned short)(u.z >> 16));
    o[6] = b2f((unsigned short)(u.w & 0xffff));
    o[7] = b2f((unsigned short)(u.w >> 16));
}
__device__ __forceinline__ uint4 pack_bf8(const float* o) {
    uint4 p;
    p.x = (uint)f2b(o[0]) | ((uint)f2b(o[1]) << 16);
    p.y = (uint)f2b(o[2]) | ((uint)f2b(o[3]) << 16);
    p.z = (uint)f2b(o[4]) | ((uint)f2b(o[5]) << 16);
    p.w = (uint)f2b(o[6]) | ((uint)f2b(o[7]) << 16);
    return p;
}

// ---------------------------------------------------------------- LayerNorm -> bf16 xn
__global__ __launch_bounds__(256) void k_ln(const float* __restrict__ x,
        const float* __restrict__ g, const float* __restrict__ bta,
        unsigned short* __restrict__ xnb, float* __restrict__ xg) {
    int wid = blockIdx.x * 4 + (threadIdx.x >> 6);
    int lane = threadIdx.x & 63;
    const float* xr = x + (size_t)wid * DIMC;
    float v[6];
    float s = 0.f, ss = 0.f;
#pragma unroll
    for (int i = 0; i < 6; i++) {
        v[i] = xr[lane + i * 64];
        s += v[i]; ss += v[i] * v[i];
    }
#pragma unroll
    for (int m = 32; m; m >>= 1) { s += __shfl_xor(s, m); ss += __shfl_xor(ss, m); }
    float mu = s * (1.f / DIMC);
    float var = ss * (1.f / DIMC) - mu * mu;
    float rstd = rsqrtf(var + 1e-5f);
    unsigned short* xnr = xnb + (size_t)wid * DIMC;
    float sn = 0.f;
#pragma unroll
    for (int i = 0; i < 6; i++) {
        int c = lane + i * 64;
        float o = (v[i] - mu) * rstd * g[c] + bta[c];
        xnr[c] = f2b(o);
        sn += o;
    }
#pragma unroll
    for (int m = 32; m; m >>= 1) sn += __shfl_xor(sn, m);
    if (lane == 0) xg[wid] = sn * (1.f / DIMC);
}

// ---------------------------------------------------------------- direction
__global__ __launch_bounds__(256) void k_dir(const float* __restrict__ xg,
        const float* __restrict__ w1, const float* __restrict__ b1,
        const float* __restrict__ w2, const float* __restrict__ b2,
        int* __restrict__ vert) {
    __shared__ float sg[32][32];
    __shared__ float red[4][4];
    int b = blockIdx.x;
    int tid = threadIdx.x;
    for (int i = tid; i < 1024; i += 256) sg[i >> 5][i & 31] = xg[b * 1024 + i];
    __syncthreads();
    float ph = 0, pv = 0, pd = 0, pa = 0;
    const float iks = 1.f / 1.0625f;   // kernel_scale = 34/32 (antialias)
    for (int p = tid; p < 1024; p += 256) {
        int y = p >> 5, xq = p & 31;
        int xl = (xq >= 1) ? xq - 1 : 1;
        int xr2 = (xq <= 30) ? xq + 1 : 30;
        float sf = (y + 0.5f) * 1.0625f - 0.5f;
        int jlo = (int)ceilf(sf - 1.0625f); if (jlo < 0) jlo = 0;
        int jhi = (int)floorf(sf + 1.0625f); if (jhi > 33) jhi = 33;
        float acc = 0.f, wsum = 0.f;
        for (int j = jlo; j <= jhi; j++) {
            float wgt = 1.f - fabsf(sf - j) * iks;
            if (wgt <= 0.f) continue;
            int ry = (j >= 1) ? ((j <= 32) ? j - 1 : 30) : 1;
            acc += wgt * fabsf(sg[ry][xr2] - sg[ry][xl]);
            wsum += wgt;
        }
        float ghr = acc / wsum;
        int yu = (y >= 1) ? y - 1 : 1;
        int yd = (y <= 30) ? y + 1 : 30;
        float sfx = (xq + 0.5f) * 1.0625f - 0.5f;
        int ilo = (int)ceilf(sfx - 1.0625f); if (ilo < 0) ilo = 0;
        int ihi = (int)floorf(sfx + 1.0625f); if (ihi > 33) ihi = 33;
        float accv = 0.f, wsv = 0.f;
        for (int i = ilo; i <= ihi; i++) {
            float wgt = 1.f - fabsf(sfx - i) * iks;
            if (wgt <= 0.f) continue;
            int rx = (i >= 1) ? ((i <= 32) ? i - 1 : 30) : 1;
            accv += wgt * fabsf(sg[yd][rx] - sg[yu][rx]);
            wsv += wgt;
        }
        float gvr = accv / wsv;
        float gd = (ghr + gvr) * 0.5f;
        float ga = fabsf(ghr - gvr);
        float cw = ((y == 0 || y == 31) ? 2.f : 3.f) * ((xq == 0 || xq == 31) ? 2.f : 3.f);
        ph += ghr * cw; pv += gvr * cw; pd += gd * cw; pa += ga * cw;
    }
#pragma unroll
    for (int m = 32; m; m >>= 1) {
        ph += __shfl_xor(ph, m); pv += __shfl_xor(pv, m);
        pd += __shfl_xor(pd, m); pa += __shfl_xor(pa, m);
    }
    int wv = tid >> 6;
    if ((tid & 63) == 0) { red[wv][0] = ph; red[wv][1] = pv; red[wv][2] = pd; red[wv][3] = pa; }
    __syncthreads();
    if (tid == 0) {
        float sc[4];
        for (int k = 0; k < 4; k++)
            sc[k] = (red[0][k] + red[1][k] + red[2][k] + red[3][k]) * (1.f / 9216.f);
        float hdn[32];
        for (int j = 0; j < 32; j++) {
            float a = b1[j];
            for (int i = 0; i < 4; i++) a += sc[i] * w1[i * 32 + j];
            hdn[j] = a > 0.f ? a : 0.f;
        }
        float best = -1e30f; int bi = 0;
        for (int k = 0; k < 4; k++) {
            float a = b2[k];
            for (int j = 0; j < 32; j++) a += hdn[j] * w2[j * 4 + k];
            if (a > best) { best = a; bi = k; }
        }
        vert[b] = (bi == 1) ? 1 : 0;
    }
}

// ---------------------------------------------------------------- weight prep: W[K][N] f32 -> WT[N][K] bf16
__global__ __launch_bounds__(256) void k_wt(const float* __restrict__ W,
        unsigned short* __restrict__ WT, int K, int N) {
    __shared__ float t[32][33];
    int nb = N >> 5;
    int n0 = (blockIdx.x % nb) << 5, k0 = (blockIdx.x / nb) << 5;
    int i = threadIdx.x;
    int kr = i >> 3, n4 = (i & 7) << 2;
    float4 v = *(const float4*)(W + (size_t)(k0 + kr) * N + n0 + n4);
    t[kr][n4 + 0] = v.x; t[kr][n4 + 1] = v.y; t[kr][n4 + 2] = v.z; t[kr][n4 + 3] = v.w;
    __syncthreads();
    int nr = i >> 3, k4 = (i & 7) << 2;
    ushort4 o;
    o.x = f2b(t[k4 + 0][nr]); o.y = f2b(t[k4 + 1][nr]);
    o.z = f2b(t[k4 + 2][nr]); o.w = f2b(t[k4 + 3][nr]);
    *(ushort4*)(WT + (size_t)(n0 + nr) * K + k0 + k4) = o;
}

// ---------------------------------------------------------------- MFMA GEMM
// D[op1_row][op2_row] = sum_k op1[r1][k] * op2[r2][k], 128x128 tile, 4 waves,
// 16x16x32 bf16 MFMA, K-step 32, double-buffered LDS [128][40] bf16 (pad->2-way).
// MODE 0 (in_proj): op1=inwT[1536][384], op2=xn[8192][384] (+vert row gather),
//                   out = xz_T bf16 [n][8192]
// MODE 1 (dt):      op1=dtwT[768][768], op2=xc_T[768][8192] (transposed staging),
//                   +bias+softplus, out = delta_T bf16 [n][8192]
// MODE 2 (out):     op1=y_T[768][8192] (transposed staging), op2=outwT[384][768],
//                   out = f32 [m][384] + resid
template <bool SWZ>
__device__ __forceinline__ bf16x8 frag_rd(const unsigned short* L, int rr, int lg) {
    int ch = lg << 3;
    if constexpr (SWZ) ch ^= ((rr >> 4) & 3) << 3;
    return *(const bf16x8*)&L[rr * 40 + ch];
}

template <int MODE>
__global__ __launch_bounds__(256) void k_mfma(
        const unsigned short* __restrict__ op1,
        const unsigned short* __restrict__ op2,
        void* __restrict__ outp,
        const float* __restrict__ bias,
        const float* __restrict__ resid,
        const int* __restrict__ vert) {
    constexpr int K = (MODE == 0) ? 384 : 768;
    constexpr int NK = K / 32;
    constexpr int NBN = (MODE == 0) ? 12 : (MODE == 1 ? 6 : 3);
    __shared__ unsigned short lds[2][2][128 * 40];
    int tid = threadIdx.x;
    int n0 = (blockIdx.x % NBN) << 7;
    int m0 = (blockIdx.x / NBN) << 7;

    int drow = tid >> 1, dkh = (tid & 1) << 4;      // direct staging coords
    int td = tid >> 3, ttof = (tid & 7) << 4;       // transposed staging coords
    int tsw = td ^ ((tid & 3) << 3);                // swizzled d slot (const/thread)

    size_t g1row = 0, g2row = 0;
    if constexpr (MODE == 0) {
        g1row = (size_t)(n0 + drow) * 384;
        int m = m0 + drow;
        int b = m >> 10, l = m & 1023;
        int src = vert[b] ? (((l & 31) << 5) | (l >> 5)) : l;
        g2row = ((size_t)(b << 10) + src) * 384;
    } else if constexpr (MODE == 1) {
        g1row = (size_t)(n0 + drow) * 768;
    } else {
        g2row = (size_t)(n0 + drow) * 768;
    }

    f32x4 acc[4][4];
    f32x4 zero = {0.f, 0.f, 0.f, 0.f};
#pragma unroll
    for (int i = 0; i < 4; i++)
#pragma unroll
        for (int j = 0; j < 4; j++) acc[i][j] = zero;

    uint4 s1a, s1b, s2a, s2b;

#define LOAD1(k0_)                                                              \
    { if constexpr (MODE == 2) {                                                \
          const unsigned short* p = op1 + (size_t)((k0_) + td) * 8192 + m0 + ttof; \
          s1a = *(const uint4*)p; s1b = *(const uint4*)(p + 8);                 \
      } else {                                                                  \
          const unsigned short* p = op1 + g1row + (k0_) + dkh;                  \
          s1a = *(const uint4*)p; s1b = *(const uint4*)(p + 8);                 \
      } }
#define LOAD2(k0_)                                                              \
    { if constexpr (MODE == 1) {                                                \
          const unsigned short* p = op2 + (size_t)((k0_) + td) * 8192 + m0 + ttof; \
          s2a = *(const uint4*)p; s2b = *(const uint4*)(p + 8);                 \
      } else {                                                                  \
          const unsigned short* p = op2 + g2row + (k0_) + dkh;                  \
          s2a = *(const uint4*)p; s2b = *(const uint4*)(p + 8);                 \
      } }
#define WRITE1(buf_)                                                            \
    { unsigned short* L = &lds[buf_][0][0];                                     \
      if constexpr (MODE == 2) {                                                \
          const unsigned short* va = (const unsigned short*)&s1a;               \
          const unsigned short* vb = (const unsigned short*)&s1b;               \
          _Pragma("unroll") for (int j = 0; j < 8; j++) L[(ttof + j) * 40 + tsw] = va[j]; \
          _Pragma("unroll") for (int j = 0; j < 8; j++) L[(ttof + 8 + j) * 40 + tsw] = vb[j]; \
      } else {                                                                  \
          *(uint4*)&L[drow * 40 + dkh] = s1a;                                   \
          *(uint4*)&L[drow * 40 + dkh + 8] = s1b;                               \
      } }
#define WRITE2(buf_)                                                            \
    { unsigned short* L = &lds[buf_][1][0];                                     \
      if constexpr (MODE == 1) {                                                \
          const unsigned short* va = (const unsigned short*)&s2a;               \
          const unsigned short* vb = (const unsigned short*)&s2b;               \
          _Pragma("unroll") for (int j = 0; j < 8; j++) L[(ttof + j) * 40 + tsw] = va[j]; \
          _Pragma("unroll") for (int j = 0; j < 8; j++) L[(ttof + 8 + j) * 40 + tsw] = vb[j]; \
      } else {                                                                  \
          *(uint4*)&L[drow * 40 + dkh] = s2a;                                   \
          *(uint4*)&L[drow * 40 + dkh + 8] = s2b;                               \
      } }

    int wid = tid >> 6, lane = tid & 63;
    int lr = lane & 15, lg = lane >> 4;
    int o1b = (wid >> 1) << 6;   // op1-row 64-block within tile
    int o2b = (wid & 1) << 6;    // op2-row 64-block within tile

    LOAD1(0) LOAD2(0)
    WRITE1(0) WRITE2(0)
    int cur = 0;
    for (int ks = 0; ks < NK; ks++) {
        int kn = (ks + 1) << 5;
        if (ks + 1 < NK) { LOAD1(kn) LOAD2(kn) }
        __syncthreads();
        const unsigned short* L1 = &lds[cur][0][0];
        const unsigned short* L2 = &lds[cur][1][0];
        bf16x8 f1[4], f2[4];
#pragma unroll
        for (int f = 0; f < 4; f++) f1[f] = frag_rd<(MODE == 2)>(L1, o1b + f * 16 + lr, lg);
#pragma unroll
        for (int f = 0; f < 4; f++) f2[f] = frag_rd<(MODE == 1)>(L2, o2b + f * 16 + lr, lg);
#pragma unroll
        for (int i = 0; i < 4; i++)
#pragma unroll
            for (int j = 0; j < 4; j++)
                acc[i][j] = __builtin_amdgcn_mfma_f32_16x16x32_bf16(f1[i], f2[j], acc[i][j], 0, 0, 0);
        if (ks + 1 < NK) { WRITE1(cur ^ 1) WRITE2(cur ^ 1) }
        cur ^= 1;
    }

    if constexpr (MODE <= 1) {
        unsigned short* CT = (unsigned short*)outp;
#pragma unroll
        for (int i = 0; i < 4; i++) {
            int nb_ = n0 + o1b + i * 16 + lg * 4;
#pragma unroll
            for (int j = 0; j < 4; j++) {
                int mb_ = m0 + o2b + j * 16 + lr;
#pragma unroll
                for (int r = 0; r < 4; r++) {
                    int n = nb_ + r;
                    float v = acc[i][j][r];
                    if constexpr (MODE == 1) {
                        v += bias[n];
                        v = fmaxf(v, 0.f) + log1pf(__expf(-fabsf(v)));   // softplus
                    }
                    CT[(size_t)n * 8192 + mb_] = f2b(v);
                }
            }
        }
    } else {
        float* C = (float*)outp;
#pragma unroll
        for (int i = 0; i < 4; i++) {
            int mb_ = m0 + o1b + i * 16 + lg * 4;
#pragma unroll
            for (int j = 0; j < 4; j++) {
                int n = n0 + o2b + j * 16 + lr;
#pragma unroll
                for (int r = 0; r < 4; r++) {
                    int m = mb_ + r;
                    C[(size_t)m * 384 + n] = acc[i][j][r] + resid[(size_t)m * 384 + n];
                }
            }
        }
    }
#undef LOAD1
#undef LOAD2
#undef WRITE1
#undef WRITE2
}

// ---------------------------------------------------------------- depthwise conv3 + silu
__global__ __launch_bounds__(256) void k_conv(const unsigned short* __restrict__ xzb,
        const float* __restrict__ cw, const float* __restrict__ cb,
        unsigned short* __restrict__ xcb) {
    int gc = blockIdx.x * 256 + threadIdx.x;   // 768 * 512
    int d = gc >> 9;
    int t0 = (gc & 511) << 4;
    const unsigned short* xr = xzb + (size_t)d * 8192;
    float xx[16];
    ld_bf8(xr + t0, xx);
    ld_bf8(xr + t0 + 8, xx + 8);
    int l0 = t0 & 1023;
    float xprev = (l0 != 0)    ? b2f(xr[t0 - 1])  : 0.f;
    float xnext = (l0 != 1008) ? b2f(xr[t0 + 16]) : 0.f;
    float w0 = cw[d * 3], w1 = cw[d * 3 + 1], w2 = cw[d * 3 + 2], bb = cb[d];
    float o[16];
#pragma unroll
    for (int j = 0; j < 16; j++) {
        float v = bb + w1 * xx[j];
        v += w0 * ((j == 0) ? xprev : xx[j - 1]);
        v += w2 * ((j == 15) ? xnext : xx[j + 1]);
        float sig = 1.f / (1.f + __expf(-v));
        o[j] = v * sig;
    }
    *(uint4*)(xcb + (size_t)d * 8192 + t0)     = pack_bf8(o);
    *(uint4*)(xcb + (size_t)d * 8192 + t0 + 8) = pack_bf8(o + 8);
}

// ---------------------------------------------------------------- x_proj
__global__ __launch_bounds__(256) void k_xproj(const unsigned short* __restrict__ xcb,
        const float* __restrict__ xw, float* __restrict__ BC) {
    __shared__ unsigned short sx[32][64];
    int r0 = blockIdx.x * 64;
    int tid = threadIdx.x;
    int n = tid & 31, rg = tid >> 5;
    float acc[8] = {};
    for (int k0 = 0; k0 < 768; k0 += 32) {
        int kk = tid >> 3, r8 = (tid & 7) << 3;
        *(uint4*)&sx[kk][r8] = *(const uint4*)(xcb + (size_t)(k0 + kk) * 8192 + r0 + r8);
        __syncthreads();
#pragma unroll 8
        for (int k2 = 0; k2 < 32; k2++) {
            float w = xw[(k0 + k2) * 32 + n];
            float xb[8];
            ld_bf8(&sx[k2][rg << 3], xb);
#pragma unroll
            for (int j = 0; j < 8; j++) acc[j] = fmaf(xb[j], w, acc[j]);
        }
        __syncthreads();
    }
    float* dst = BC + (size_t)n * 8192 + r0 + (rg << 3);
    *(float4*)dst       = make_float4(acc[0], acc[1], acc[2], acc[3]);
    *(float4*)(dst + 4) = make_float4(acc[4], acc[5], acc[6], acc[7]);
}

// ---------------------------------------------------------------- chunked scan
__global__ __launch_bounds__(256) void k_scan1(const unsigned short* __restrict__ xzb,
        const unsigned short* __restrict__ xcb, const float* __restrict__ BC,
        const float* __restrict__ A_log,
        unsigned short* __restrict__ G, float* __restrict__ sumd) {
    int blk = blockIdx.x;              // 8b * NCH * 48dg
    int dg = blk % 48;
    int c  = (blk / 48) % NCH;
    int b  = blk / (48 * NCH);
    int tid = threadIdx.x;
    int dl = tid >> 4, n = tid & 15;
    int d = dg * 16 + dl;
    float Av = -expf(A_log[d * 16 + n]);
    size_t r0 = (size_t)b * 1024 + c * CHUNK;
    const unsigned short* dptr = xzb + (size_t)d * 8192 + r0;
    const unsigned short* xptr = xcb + (size_t)d * 8192 + r0;
    const float* Bp = BC + (size_t)n * 8192 + r0;
    float h = 0.f, sd = 0.f;
    for (int t0 = 0; t0 < CHUNK; t0 += 8) {
        float dv[8], xv[8], Bv[8];
        ld_bf8(dptr + t0, dv);
        ld_bf8(xptr + t0, xv);
        *(float4*)&Bv[0] = *(const float4*)(Bp + t0);
        *(float4*)&Bv[4] = *(const float4*)(Bp + t0 + 4);
#pragma unroll
        for (int j = 0; j < 8; j++) {
            float dA = __expf(dv[j] * Av);
            h = fmaf(dA, h, dv[j] * xv[j] * Bv[j]);
            sd += dv[j];
        }
    }
    size_t gi = (((size_t)(b * NCH + c)) * 768 + d) * 16 + n;
    G[gi] = f2b(h);
    if (n == 0) sumd[(size_t)(b * NCH + c) * 768 + d] = sd;
}

__global__ __launch_bounds__(256) void k_scan2(unsigned short* __restrict__ G,
        const float* __restrict__ sumd, const float* __restrict__ A_log) {
    int blk = blockIdx.x;              // 8b * 48dg
    int dg = blk % 48, b = blk / 48;
    int tid = threadIdx.x;
    int dl = tid >> 4, n = tid & 15;
    int d = dg * 16 + dl;
    float Av = -expf(A_log[d * 16 + n]);
    float H = 0.f;
#pragma unroll
    for (int c = 0; c < NCH; c++) {
        size_t gi = (((size_t)(b * NCH + c)) * 768 + d) * 16 + n;
        float Gv = b2f(G[gi]);
        float P = __expf(Av * sumd[(size_t)(b * NCH + c) * 768 + d]);
        G[gi] = f2b(H);                // carry-in for chunk c
        H = fmaf(P, H, Gv);
    }
}

#define SCAN_LOAD(dv, xv, zv, Bv, Cv, t0)                \
    ld_bf8(dptr + (t0), dv);                             \
    ld_bf8(xptr + (t0), xv);                             \
    ld_bf8(zptr + (t0), zv);                             \
    *(float4*)&Bv[0] = *(const float4*)(Bp + (t0));      \
    *(float4*)&Bv[4] = *(const float4*)(Bp + (t0) + 4);  \
    *(float4*)&Cv[0] = *(const float4*)(Cp + (t0));      \
    *(float4*)&Cv[4] = *(const float4*)(Cp + (t0) + 4);

#define SCAN_COMP(dv, xv, zv, Bv, Cv, t0)                          \
    {                                                              \
        float yr[8];                                               \
        _Pragma("unroll")                                          \
        for (int j = 0; j < 8; j++) {                              \
            float dA = __expf(dv[j] * Av);                         \
            h = fmaf(dA, h, dv[j] * xv[j] * Bv[j]);                \
            float p = h * Cv[j];                                   \
            p += __shfl_xor(p, 1); p += __shfl_xor(p, 2);          \
            p += __shfl_xor(p, 4); p += __shfl_xor(p, 8);          \
            float zz = zv[j];                                      \
            float sig = 1.f / (1.f + __expf(-zz));                 \
            yr[j] = (p + Dv * xv[j]) * zz * sig;                   \
        }                                                          \
        if (n == 0) *(uint4*)(dptr + (t0)) = pack_bf8(yr);         \
    }

__global__ __launch_bounds__(256) void k_scan3(unsigned short* xzb,
        const unsigned short* __restrict__ xcb, const float* __restrict__ BC,
        const float* __restrict__ A_log, const float* __restrict__ Dp,
        const unsigned short* __restrict__ G) {
    int blk = blockIdx.x;              // 8b * NCH * 48dg
    int dg = blk % 48;
    int c  = (blk / 48) % NCH;
    int b  = blk / (48 * NCH);
    int tid = threadIdx.x;
    int dl = tid >> 4, n = tid & 15;
    int d = dg * 16 + dl;
    float Av = -expf(A_log[d * 16 + n]);
    float Dv = Dp[d];
    size_t r0 = (size_t)b * 1024 + c * CHUNK;
    unsigned short* dptr       = xzb + (size_t)d * 8192 + r0;          // delta -> y
    const unsigned short* zptr = xzb + (size_t)(768 + d) * 8192 + r0;  // z
    const unsigned short* xptr = xcb + (size_t)d * 8192 + r0;          // xc
    const float* Bp = BC + (size_t)n * 8192 + r0;
    const float* Cp = BC + (size_t)(16 + n) * 8192 + r0;
    float h = b2f(G[(((size_t)(b * NCH + c)) * 768 + d) * 16 + n]);
    float dvA[8], xvA[8], zvA[8], BvA[8], CvA[8];
    float dvB[8], xvB[8], zvB[8], BvB[8], CvB[8];
    SCAN_LOAD(dvA, xvA, zvA, BvA, CvA, 0)
    for (int t0 = 0; t0 < CHUNK; t0 += 16) {
        SCAN_LOAD(dvB, xvB, zvB, BvB, CvB, t0 + 8)
        SCAN_COMP(dvA, xvA, zvA, BvA, CvA, t0)
        if (t0 + 16 < CHUNK) { SCAN_LOAD(dvA, xvA, zvA, BvA, CvA, t0 + 16) }
        SCAN_COMP(dvB, xvB, zvB, BvB, CvB, t0 + 8)
    }
}

// ---------------------------------------------------------------- launch
extern "C" void kernel_launch(void* const* d_in, const int* in_sizes, int n_in,
                              void* d_out, int out_size, void* d_ws, size_t ws_size,
                              hipStream_t stream) {
    const float* x    = (const float*)d_in[0];
    const float* ln_g = (const float*)d_in[1];
    const float* ln_b = (const float*)d_in[2];
    const float* mw1  = (const float*)d_in[3];
    const float* mb1  = (const float*)d_in[4];
    const float* mw2  = (const float*)d_in[5];
    const float* mb2  = (const float*)d_in[6];
    const float* inw  = (const float*)d_in[7];
    const float* cw   = (const float*)d_in[8];
    const float* cb   = (const float*)d_in[9];
    const float* xpw  = (const float*)d_in[10];
    const float* dtw  = (const float*)d_in[11];
    const float* dtb  = (const float*)d_in[12];
    const float* alog = (const float*)d_in[13];
    const float* Dp   = (const float*)d_in[14];
    const float* outw = (const float*)d_in[15];
    float* out = (float*)d_out;

    // ws: 31.0 MB total (28.1 proven safe; +2.95 MB bf16 W^T buffers)
    char* ws = (char*)d_ws;
    unsigned short* xzb = (unsigned short*)(ws);            // xz_T [1536][8192] bf16
    float* BCb = (float*)(ws + 25165824);                   // BC_T [32][8192] f32
    float* xg  = (float*)(ws + 26214400);                   // 8192*4
    int*  vert = (int*)(ws + 26247168);                     // 8*4
    unsigned short* G = (unsigned short*)(ws + 26248192);   // [8][NCH][768][16] bf16
    float* sumd = (float*)(ws + 27821056);                  // [8][NCH][768] f32
    unsigned short* inwT  = (unsigned short*)(ws + 28017664);  // [1536][384] bf16
    unsigned short* dtwT  = (unsigned short*)(ws + 29197312);  // [768][768]  bf16
    unsigned short* outwT = (unsigned short*)(ws + 30376960);  // [384][768]  bf16 (ends 30,966,784)

    unsigned short* xnb = (unsigned short*)d_out;  // d_out: xn(bf16) -> xc_T(bf16) -> out(f32)
    unsigned short* xcb = (unsigned short*)d_out;

    k_ln<<<2048, 256, 0, stream>>>(x, ln_g, ln_b, xnb, xg);
    k_dir<<<8, 256, 0, stream>>>(xg, mw1, mb1, mw2, mb2, vert);
    k_wt<<<576, 256, 0, stream>>>(inw, inwT, 384, 1536);
    k_wt<<<576, 256, 0, stream>>>(dtw, dtwT, 768, 768);
    k_wt<<<288, 256, 0, stream>>>(outw, outwT, 768, 384);
    // xz_T = (gather(xn) @ in_proj)^T
    k_mfma<0><<<12 * 64, 256, 0, stream>>>(inwT, xnb, xzb, nullptr, nullptr, vert);
    k_conv<<<1536, 256, 0, stream>>>(xzb, cw, cb, xcb);
    k_xproj<<<128, 256, 0, stream>>>(xcb, xpw, BCb);
    // delta_T = softplus(xc @ dt_w + dt_b)^T  (over xz_T ch<768)
    k_mfma<1><<<6 * 64, 256, 0, stream>>>(dtwT, xcb, xzb, dtb, nullptr, nullptr);
    k_scan1<<<8 * NCH * 48, 256, 0, stream>>>(xzb, xcb, BCb, alog, G, sumd);
    k_scan2<<<8 * 48, 256, 0, stream>>>(G, sumd, alog);
    k_scan3<<<8 * NCH * 48, 256, 0, stream>>>(xzb, xcb, BCb, alog, Dp, G);
    // out = x + y @ out_proj  (y read transposed from xz_T ch<768)
    k_mfma<2><<<3 * 64, 256, 0, stream>>>(xzb, outwT, out, nullptr, x, nullptr);
}

// Round 7
// 306.791 us; speedup vs baseline: 2.1488x; 1.1188x over previous
//
#include <hip/hip_runtime.h>
#include <hip/hip_bf16.h>
#include <math.h>

#define NPOS 8192   // B*H*W = 8*32*32
#define DIMC 384
#define DIN 768
#define DST 16
#define CHUNK 64
#define NCH 16      // 1024 / CHUNK

typedef unsigned int uint;
typedef __attribute__((ext_vector_type(8))) short bf16x8;
typedef __attribute__((ext_vector_type(4))) float f32x4;

__device__ __forceinline__ float b2f(unsigned short u) {
    return __uint_as_float(((unsigned int)u) << 16);
}
__device__ __forceinline__ unsigned short f2b(float f) {
    unsigned int u = __float_as_uint(f);
    u = (u + 0x7FFFu + ((u >> 16) & 1u)) >> 16;   // round-to-nearest-even
    return (unsigned short)u;
}
// 1-instruction packed f32->bf16 (RNE)
__device__ __forceinline__ uint cvt_pk(float lo, float hi) {
    uint r;
    asm("v_cvt_pk_bf16_f32 %0, %1, %2" : "=v"(r) : "v"(lo), "v"(hi));
    return r;
}
__device__ __forceinline__ unsigned short f2b1(float f) {
    return (unsigned short)cvt_pk(f, f);
}
// fast reciprocal (~1ulp medium precision, plenty for 0.099 tolerance)
__device__ __forceinline__ float frcp(float x) {
    float r;
    asm("v_rcp_f32 %0, %1" : "=v"(r) : "v"(x));
    return r;
}
__device__ __forceinline__ void ld_bf8(const unsigned short* p, float* o) {
    uint4 u = *(const uint4*)p;
    o[0] = b2f((unsigned short)(u.x & 0xffff));
    o[1] = b2f((unsigned short)(u.x >> 16));
    o[2] = b2f((unsigned short)(u.y & 0xffff));
    o[3] = b2f((unsigned short)(u.y >> 16));
    o[4] = b2f((unsigned short)(u.z & 0xffff));
    o[5] = b2f((unsigned short)(u.z >> 16));
    o[6] = b2f((unsigned short)(u.w & 0xffff));
    o[7] = b2f((unsigned short)(u.w >> 16));
}
__device__ __forceinline__ uint4 pack_bf8(const float* o) {
    uint4 p;
    p.x = cvt_pk(o[0], o[1]);
    p.y = cvt_pk(o[2], o[3]);
    p.z = cvt_pk(o[4], o[5]);
    p.w = cvt_pk(o[6], o[7]);
    return p;
}
// butterfly sum across 16-lane row via DPP row_ror (rotation reduce, exact for +)
__device__ __forceinline__ float row_reduce16(float p) {
    int t;
    t = __builtin_amdgcn_update_dpp(0, __float_as_int(p), 0x128, 0xf, 0xf, true);
    p += __int_as_float(t);
    t = __builtin_amdgcn_update_dpp(0, __float_as_int(p), 0x124, 0xf, 0xf, true);
    p += __int_as_float(t);
    t = __builtin_amdgcn_update_dpp(0, __float_as_int(p), 0x122, 0xf, 0xf, true);
    p += __int_as_float(t);
    t = __builtin_amdgcn_update_dpp(0, __float_as_int(p), 0x121, 0xf, 0xf, true);
    p += __int_as_float(t);
    return p;
}

// ---------------------------------------------------------------- LayerNorm -> bf16 xn
__global__ __launch_bounds__(256) void k_ln(const float* __restrict__ x,
        const float* __restrict__ g, const float* __restrict__ bta,
        unsigned short* __restrict__ xnb, float* __restrict__ xg) {
    int wid = blockIdx.x * 4 + (threadIdx.x >> 6);
    int lane = threadIdx.x & 63;
    const float* xr = x + (size_t)wid * DIMC;
    float v[6];
    float s = 0.f, ss = 0.f;
#pragma unroll
    for (int i = 0; i < 6; i++) {
        v[i] = xr[lane + i * 64];
        s += v[i]; ss += v[i] * v[i];
    }
#pragma unroll
    for (int m = 32; m; m >>= 1) { s += __shfl_xor(s, m); ss += __shfl_xor(ss, m); }
    float mu = s * (1.f / DIMC);
    float var = ss * (1.f / DIMC) - mu * mu;
    float rstd = rsqrtf(var + 1e-5f);
    unsigned short* xnr = xnb + (size_t)wid * DIMC;
    float sn = 0.f;
#pragma unroll
    for (int i = 0; i < 6; i++) {
        int c = lane + i * 64;
        float o = (v[i] - mu) * rstd * g[c] + bta[c];
        xnr[c] = f2b1(o);
        sn += o;
    }
#pragma unroll
    for (int m = 32; m; m >>= 1) sn += __shfl_xor(sn, m);
    if (lane == 0) xg[wid] = sn * (1.f / DIMC);
}

// ---------------------------------------------------------------- direction
__global__ __launch_bounds__(256) void k_dir(const float* __restrict__ xg,
        const float* __restrict__ w1, const float* __restrict__ b1,
        const float* __restrict__ w2, const float* __restrict__ b2,
        int* __restrict__ vert) {
    __shared__ float sg[32][32];
    __shared__ float red[4][4];
    int b = blockIdx.x;
    int tid = threadIdx.x;
    for (int i = tid; i < 1024; i += 256) sg[i >> 5][i & 31] = xg[b * 1024 + i];
    __syncthreads();
    float ph = 0, pv = 0, pd = 0, pa = 0;
    const float iks = 1.f / 1.0625f;   // kernel_scale = 34/32 (antialias)
    for (int p = tid; p < 1024; p += 256) {
        int y = p >> 5, xq = p & 31;
        int xl = (xq >= 1) ? xq - 1 : 1;
        int xr2 = (xq <= 30) ? xq + 1 : 30;
        float sf = (y + 0.5f) * 1.0625f - 0.5f;
        int jlo = (int)ceilf(sf - 1.0625f); if (jlo < 0) jlo = 0;
        int jhi = (int)floorf(sf + 1.0625f); if (jhi > 33) jhi = 33;
        float acc = 0.f, wsum = 0.f;
        for (int j = jlo; j <= jhi; j++) {
            float wgt = 1.f - fabsf(sf - j) * iks;
            if (wgt <= 0.f) continue;
            int ry = (j >= 1) ? ((j <= 32) ? j - 1 : 30) : 1;
            acc += wgt * fabsf(sg[ry][xr2] - sg[ry][xl]);
            wsum += wgt;
        }
        float ghr = acc / wsum;
        int yu = (y >= 1) ? y - 1 : 1;
        int yd = (y <= 30) ? y + 1 : 30;
        float sfx = (xq + 0.5f) * 1.0625f - 0.5f;
        int ilo = (int)ceilf(sfx - 1.0625f); if (ilo < 0) ilo = 0;
        int ihi = (int)floorf(sfx + 1.0625f); if (ihi > 33) ihi = 33;
        float accv = 0.f, wsv = 0.f;
        for (int i = ilo; i <= ihi; i++) {
            float wgt = 1.f - fabsf(sfx - i) * iks;
            if (wgt <= 0.f) continue;
            int rx = (i >= 1) ? ((i <= 32) ? i - 1 : 30) : 1;
            accv += wgt * fabsf(sg[yd][rx] - sg[yu][rx]);
            wsv += wgt;
        }
        float gvr = accv / wsv;
        float gd = (ghr + gvr) * 0.5f;
        float ga = fabsf(ghr - gvr);
        float cw = ((y == 0 || y == 31) ? 2.f : 3.f) * ((xq == 0 || xq == 31) ? 2.f : 3.f);
        ph += ghr * cw; pv += gvr * cw; pd += gd * cw; pa += ga * cw;
    }
#pragma unroll
    for (int m = 32; m; m >>= 1) {
        ph += __shfl_xor(ph, m); pv += __shfl_xor(pv, m);
        pd += __shfl_xor(pd, m); pa += __shfl_xor(pa, m);
    }
    int wv = tid >> 6;
    if ((tid & 63) == 0) { red[wv][0] = ph; red[wv][1] = pv; red[wv][2] = pd; red[wv][3] = pa; }
    __syncthreads();
    if (tid == 0) {
        float sc[4];
        for (int k = 0; k < 4; k++)
            sc[k] = (red[0][k] + red[1][k] + red[2][k] + red[3][k]) * (1.f / 9216.f);
        float hdn[32];
        for (int j = 0; j < 32; j++) {
            float a = b1[j];
            for (int i = 0; i < 4; i++) a += sc[i] * w1[i * 32 + j];
            hdn[j] = a > 0.f ? a : 0.f;
        }
        float best = -1e30f; int bi = 0;
        for (int k = 0; k < 4; k++) {
            float a = b2[k];
            for (int j = 0; j < 32; j++) a += hdn[j] * w2[j * 4 + k];
            if (a > best) { best = a; bi = k; }
        }
        vert[b] = (bi == 1) ? 1 : 0;
    }
}

// ---------------------------------------------------------------- weight prep: W[K][N] f32 -> WT[N][K] bf16
__global__ __launch_bounds__(256) void k_wt(const float* __restrict__ W,
        unsigned short* __restrict__ WT, int K, int N) {
    __shared__ float t[32][33];
    int nb = N >> 5;
    int n0 = (blockIdx.x % nb) << 5, k0 = (blockIdx.x / nb) << 5;
    int i = threadIdx.x;
    int kr = i >> 3, n4 = (i & 7) << 2;
    float4 v = *(const float4*)(W + (size_t)(k0 + kr) * N + n0 + n4);
    t[kr][n4 + 0] = v.x; t[kr][n4 + 1] = v.y; t[kr][n4 + 2] = v.z; t[kr][n4 + 3] = v.w;
    __syncthreads();
    int nr = i >> 3, k4 = (i & 7) << 2;
    ushort4 o;
    o.x = f2b1(t[k4 + 0][nr]); o.y = f2b1(t[k4 + 1][nr]);
    o.z = f2b1(t[k4 + 2][nr]); o.w = f2b1(t[k4 + 3][nr]);
    *(ushort4*)(WT + (size_t)(n0 + nr) * K + k0 + k4) = o;
}

// ---------------------------------------------------------------- MFMA GEMM
template <bool SWZ>
__device__ __forceinline__ bf16x8 frag_rd(const unsigned short* L, int rr, int lg) {
    int ch = lg << 3;
    if constexpr (SWZ) ch ^= ((rr >> 4) & 3) << 3;
    return *(const bf16x8*)&L[rr * 40 + ch];
}

template <int MODE>
__global__ __launch_bounds__(256) void k_mfma(
        const unsigned short* __restrict__ op1,
        const unsigned short* __restrict__ op2,
        void* __restrict__ outp,
        const float* __restrict__ bias,
        const float* __restrict__ resid,
        const int* __restrict__ vert) {
    constexpr int K = (MODE == 0) ? 384 : 768;
    constexpr int NK = K / 32;
    constexpr int NBN = (MODE == 0) ? 12 : (MODE == 1 ? 6 : 3);
    __shared__ unsigned short lds[2][2][128 * 40];
    int tid = threadIdx.x;
    int n0 = (blockIdx.x % NBN) << 7;
    int m0 = (blockIdx.x / NBN) << 7;

    int drow = tid >> 1, dkh = (tid & 1) << 4;      // direct staging coords
    int td = tid >> 3, ttof = (tid & 7) << 4;       // transposed staging coords
    int tsw = td ^ ((tid & 3) << 3);                // swizzled d slot (const/thread)

    size_t g1row = 0, g2row = 0;
    if constexpr (MODE == 0) {
        g1row = (size_t)(n0 + drow) * 384;
        int m = m0 + drow;
        int b = m >> 10, l = m & 1023;
        int src = vert[b] ? (((l & 31) << 5) | (l >> 5)) : l;
        g2row = ((size_t)(b << 10) + src) * 384;
    } else if constexpr (MODE == 1) {
        g1row = (size_t)(n0 + drow) * 768;
    } else {
        g2row = (size_t)(n0 + drow) * 768;
    }

    f32x4 acc[4][4];
    f32x4 zero = {0.f, 0.f, 0.f, 0.f};
#pragma unroll
    for (int i = 0; i < 4; i++)
#pragma unroll
        for (int j = 0; j < 4; j++) acc[i][j] = zero;

    uint4 s1a, s1b, s2a, s2b;

#define LOAD1(k0_)                                                              \
    { if constexpr (MODE == 2) {                                                \
          const unsigned short* p = op1 + (size_t)((k0_) + td) * 8192 + m0 + ttof; \
          s1a = *(const uint4*)p; s1b = *(const uint4*)(p + 8);                 \
      } else {                                                                  \
          const unsigned short* p = op1 + g1row + (k0_) + dkh;                  \
          s1a = *(const uint4*)p; s1b = *(const uint4*)(p + 8);                 \
      } }
#define LOAD2(k0_)                                                              \
    { if constexpr (MODE == 1) {                                                \
          const unsigned short* p = op2 + (size_t)((k0_) + td) * 8192 + m0 + ttof; \
          s2a = *(const uint4*)p; s2b = *(const uint4*)(p + 8);                 \
      } else {                                                                  \
          const unsigned short* p = op2 + g2row + (k0_) + dkh;                  \
          s2a = *(const uint4*)p; s2b = *(const uint4*)(p + 8);                 \
      } }
#define WRITE1(buf_)                                                            \
    { unsigned short* L = &lds[buf_][0][0];                                     \
      if constexpr (MODE == 2) {                                                \
          const unsigned short* va = (const unsigned short*)&s1a;               \
          const unsigned short* vb = (const unsigned short*)&s1b;               \
          _Pragma("unroll") for (int j = 0; j < 8; j++) L[(ttof + j) * 40 + tsw] = va[j]; \
          _Pragma("unroll") for (int j = 0; j < 8; j++) L[(ttof + 8 + j) * 40 + tsw] = vb[j]; \
      } else {                                                                  \
          *(uint4*)&L[drow * 40 + dkh] = s1a;                                   \
          *(uint4*)&L[drow * 40 + dkh + 8] = s1b;                               \
      } }
#define WRITE2(buf_)                                                            \
    { unsigned short* L = &lds[buf_][1][0];                                     \
      if constexpr (MODE == 1) {                                                \
          const unsigned short* va = (const unsigned short*)&s2a;               \
          const unsigned short* vb = (const unsigned short*)&s2b;               \
          _Pragma("unroll") for (int j = 0; j < 8; j++) L[(ttof + j) * 40 + tsw] = va[j]; \
          _Pragma("unroll") for (int j = 0; j < 8; j++) L[(ttof + 8 + j) * 40 + tsw] = vb[j]; \
      } else {                                                                  \
          *(uint4*)&L[drow * 40 + dkh] = s2a;                                   \
          *(uint4*)&L[drow * 40 + dkh + 8] = s2b;                               \
      } }

    int wid = tid >> 6, lane = tid & 63;
    int lr = lane & 15, lg = lane >> 4;
    int o1b = (wid >> 1) << 6;   // op1-row 64-block within tile
    int o2b = (wid & 1) << 6;    // op2-row 64-block within tile

    LOAD1(0) LOAD2(0)
    WRITE1(0) WRITE2(0)
    int cur = 0;
    for (int ks = 0; ks < NK; ks++) {
        int kn = (ks + 1) << 5;
        if (ks + 1 < NK) { LOAD1(kn) LOAD2(kn) }
        __syncthreads();
        const unsigned short* L1 = &lds[cur][0][0];
        const unsigned short* L2 = &lds[cur][1][0];
        bf16x8 f1[4], f2[4];
#pragma unroll
        for (int f = 0; f < 4; f++) f1[f] = frag_rd<(MODE == 2)>(L1, o1b + f * 16 + lr, lg);
#pragma unroll
        for (int f = 0; f < 4; f++) f2[f] = frag_rd<(MODE == 1)>(L2, o2b + f * 16 + lr, lg);
#pragma unroll
        for (int i = 0; i < 4; i++)
#pragma unroll
            for (int j = 0; j < 4; j++)
                acc[i][j] = __builtin_amdgcn_mfma_f32_16x16x32_bf16(f1[i], f2[j], acc[i][j], 0, 0, 0);
        if (ks + 1 < NK) { WRITE1(cur ^ 1) WRITE2(cur ^ 1) }
        cur ^= 1;
    }

    if constexpr (MODE <= 1) {
        unsigned short* CT = (unsigned short*)outp;
#pragma unroll
        for (int i = 0; i < 4; i++) {
            int nb_ = n0 + o1b + i * 16 + lg * 4;
#pragma unroll
            for (int j = 0; j < 4; j++) {
                int mb_ = m0 + o2b + j * 16 + lr;
#pragma unroll
                for (int r = 0; r < 4; r++) {
                    int n = nb_ + r;
                    float v = acc[i][j][r];
                    if constexpr (MODE == 1) {
                        v += bias[n];
                        v = fmaxf(v, 0.f) + __logf(1.f + __expf(-fabsf(v)));   // softplus
                    }
                    CT[(size_t)n * 8192 + mb_] = f2b1(v);
                }
            }
        }
    } else {
        float* C = (float*)outp;
#pragma unroll
        for (int i = 0; i < 4; i++) {
            int mb_ = m0 + o1b + i * 16 + lg * 4;
#pragma unroll
            for (int j = 0; j < 4; j++) {
                int n = n0 + o2b + j * 16 + lr;
#pragma unroll
                for (int r = 0; r < 4; r++) {
                    int m = mb_ + r;
                    C[(size_t)m * 384 + n] = acc[i][j][r] + resid[(size_t)m * 384 + n];
                }
            }
        }
    }
#undef LOAD1
#undef LOAD2
#undef WRITE1
#undef WRITE2
}

// ---------------------------------------------------------------- depthwise conv3 + silu
__global__ __launch_bounds__(256) void k_conv(const unsigned short* __restrict__ xzb,
        const float* __restrict__ cw, const float* __restrict__ cb,
        unsigned short* __restrict__ xcb) {
    int gc = blockIdx.x * 256 + threadIdx.x;   // 768 * 512
    int d = gc >> 9;
    int t0 = (gc & 511) << 4;
    const unsigned short* xr = xzb + (size_t)d * 8192;
    float xx[16];
    ld_bf8(xr + t0, xx);
    ld_bf8(xr + t0 + 8, xx + 8);
    int l0 = t0 & 1023;
    float xprev = (l0 != 0)    ? b2f(xr[t0 - 1])  : 0.f;
    float xnext = (l0 != 1008) ? b2f(xr[t0 + 16]) : 0.f;
    float w0 = cw[d * 3], w1 = cw[d * 3 + 1], w2 = cw[d * 3 + 2], bb = cb[d];
    float o[16];
#pragma unroll
    for (int j = 0; j < 16; j++) {
        float v = bb + w1 * xx[j];
        v += w0 * ((j == 0) ? xprev : xx[j - 1]);
        v += w2 * ((j == 15) ? xnext : xx[j + 1]);
        o[j] = v * frcp(1.f + __expf(-v));
    }
    *(uint4*)(xcb + (size_t)d * 8192 + t0)     = pack_bf8(o);
    *(uint4*)(xcb + (size_t)d * 8192 + t0 + 8) = pack_bf8(o + 8);
}

// ---------------------------------------------------------------- x_proj
__global__ __launch_bounds__(256) void k_xproj(const unsigned short* __restrict__ xcb,
        const float* __restrict__ xw, float* __restrict__ BC) {
    __shared__ unsigned short sx[32][64];
    int r0 = blockIdx.x * 64;
    int tid = threadIdx.x;
    int n = tid & 31, rg = tid >> 5;
    float acc[8] = {};
    for (int k0 = 0; k0 < 768; k0 += 32) {
        int kk = tid >> 3, r8 = (tid & 7) << 3;
        *(uint4*)&sx[kk][r8] = *(const uint4*)(xcb + (size_t)(k0 + kk) * 8192 + r0 + r8);
        __syncthreads();
#pragma unroll 8
        for (int k2 = 0; k2 < 32; k2++) {
            float w = xw[(k0 + k2) * 32 + n];
            float xb[8];
            ld_bf8(&sx[k2][rg << 3], xb);
#pragma unroll
            for (int j = 0; j < 8; j++) acc[j] = fmaf(xb[j], w, acc[j]);
        }
        __syncthreads();
    }
    float* dst = BC + (size_t)n * 8192 + r0 + (rg << 3);
    *(float4*)dst       = make_float4(acc[0], acc[1], acc[2], acc[3]);
    *(float4*)(dst + 4) = make_float4(acc[4], acc[5], acc[6], acc[7]);
}

// ---------------------------------------------------------------- chunked scan
__global__ __launch_bounds__(256) void k_scan1(const unsigned short* __restrict__ xzb,
        const unsigned short* __restrict__ xcb, const float* __restrict__ BC,
        const float* __restrict__ A_log,
        unsigned short* __restrict__ G, float* __restrict__ sumd) {
    int blk = blockIdx.x;              // 8b * NCH * 48dg
    int dg = blk % 48;
    int c  = (blk / 48) % NCH;
    int b  = blk / (48 * NCH);
    int tid = threadIdx.x;
    int dl = tid >> 4, n = tid & 15;
    int d = dg * 16 + dl;
    float Av = -expf(A_log[d * 16 + n]);
    size_t r0 = (size_t)b * 1024 + c * CHUNK;
    const unsigned short* dptr = xzb + (size_t)d * 8192 + r0;
    const unsigned short* xptr = xcb + (size_t)d * 8192 + r0;
    const float* Bp = BC + (size_t)n * 8192 + r0;
    float h = 0.f, sd = 0.f;
    for (int t0 = 0; t0 < CHUNK; t0 += 8) {
        float dv[8], xv[8], Bv[8];
        ld_bf8(dptr + t0, dv);
        ld_bf8(xptr + t0, xv);
        *(float4*)&Bv[0] = *(const float4*)(Bp + t0);
        *(float4*)&Bv[4] = *(const float4*)(Bp + t0 + 4);
#pragma unroll
        for (int j = 0; j < 8; j++) {
            float dA = __expf(dv[j] * Av);
            h = fmaf(dA, h, dv[j] * xv[j] * Bv[j]);
            sd += dv[j];
        }
    }
    size_t gi = (((size_t)(b * NCH + c)) * 768 + d) * 16 + n;
    G[gi] = f2b1(h);
    if (n == 0) sumd[(size_t)(b * NCH + c) * 768 + d] = sd;
}

__global__ __launch_bounds__(256) void k_scan2(unsigned short* __restrict__ G,
        const float* __restrict__ sumd, const float* __restrict__ A_log) {
    int blk = blockIdx.x;              // 8b * 48dg
    int dg = blk % 48, b = blk / 48;
    int tid = threadIdx.x;
    int dl = tid >> 4, n = tid & 15;
    int d = dg * 16 + dl;
    float Av = -expf(A_log[d * 16 + n]);
    float H = 0.f;
#pragma unroll
    for (int c = 0; c < NCH; c++) {
        size_t gi = (((size_t)(b * NCH + c)) * 768 + d) * 16 + n;
        float Gv = b2f(G[gi]);
        float P = __expf(Av * sumd[(size_t)(b * NCH + c) * 768 + d]);
        G[gi] = f2b1(H);               // carry-in for chunk c
        H = fmaf(P, H, Gv);
    }
}

#define SCAN_LOAD(dv, xv, zv, Bv, Cv, t0)                \
    ld_bf8(dptr + (t0), dv);                             \
    ld_bf8(xptr + (t0), xv);                             \
    ld_bf8(zptr + (t0), zv);                             \
    *(float4*)&Bv[0] = *(const float4*)(Bp + (t0));      \
    *(float4*)&Bv[4] = *(const float4*)(Bp + (t0) + 4);  \
    *(float4*)&Cv[0] = *(const float4*)(Cp + (t0));      \
    *(float4*)&Cv[4] = *(const float4*)(Cp + (t0) + 4);

// finish computed by all lanes (no divergent serialization); store masked
#define SCAN_COMP(dv, xv, zv, Bv, Cv, t0)                          \
    {                                                              \
        float yr[8];                                               \
        _Pragma("unroll")                                          \
        for (int j = 0; j < 8; j++) {                              \
            float dA = __expf(dv[j] * Av);                         \
            h = fmaf(dA, h, dv[j] * xv[j] * Bv[j]);                \
            float p = row_reduce16(h * Cv[j]);                     \
            float zz = zv[j];                                      \
            float sig = frcp(1.f + __expf(-zz));                   \
            yr[j] = fmaf(Dv, xv[j], p) * zz * sig;                 \
        }                                                          \
        if (n == 0) *(uint4*)(dptr + (t0)) = pack_bf8(yr);         \
    }

__global__ __launch_bounds__(256) void k_scan3(unsigned short* xzb,
        const unsigned short* __restrict__ xcb, const float* __restrict__ BC,
        const float* __restrict__ A_log, const float* __restrict__ Dp,
        const unsigned short* __restrict__ G) {
    int blk = blockIdx.x;              // 8b * NCH * 48dg
    int dg = blk % 48;
    int c  = (blk / 48) % NCH;
    int b  = blk / (48 * NCH);
    int tid = threadIdx.x;
    int dl = tid >> 4, n = tid & 15;
    int d = dg * 16 + dl;
    float Av = -expf(A_log[d * 16 + n]);
    float Dv = Dp[d];
    size_t r0 = (size_t)b * 1024 + c * CHUNK;
    unsigned short* dptr       = xzb + (size_t)d * 8192 + r0;          // delta -> y
    const unsigned short* zptr = xzb + (size_t)(768 + d) * 8192 + r0;  // z
    const unsigned short* xptr = xcb + (size_t)d * 8192 + r0;          // xc
    const float* Bp = BC + (size_t)n * 8192 + r0;
    const float* Cp = BC + (size_t)(16 + n) * 8192 + r0;
    float h = b2f(G[(((size_t)(b * NCH + c)) * 768 + d) * 16 + n]);
    float dvA[8], xvA[8], zvA[8], BvA[8], CvA[8];
    float dvB[8], xvB[8], zvB[8], BvB[8], CvB[8];
    SCAN_LOAD(dvA, xvA, zvA, BvA, CvA, 0)
    for (int t0 = 0; t0 < CHUNK; t0 += 16) {
        SCAN_LOAD(dvB, xvB, zvB, BvB, CvB, t0 + 8)
        SCAN_COMP(dvA, xvA, zvA, BvA, CvA, t0)
        if (t0 + 16 < CHUNK) { SCAN_LOAD(dvA, xvA, zvA, BvA, CvA, t0 + 16) }
        SCAN_COMP(dvB, xvB, zvB, BvB, CvB, t0 + 8)
    }
}

// ---------------------------------------------------------------- launch
extern "C" void kernel_launch(void* const* d_in, const int* in_sizes, int n_in,
                              void* d_out, int out_size, void* d_ws, size_t ws_size,
                              hipStream_t stream) {
    const float* x    = (const float*)d_in[0];
    const float* ln_g = (const float*)d_in[1];
    const float* ln_b = (const float*)d_in[2];
    const float* mw1  = (const float*)d_in[3];
    const float* mb1  = (const float*)d_in[4];
    const float* mw2  = (const float*)d_in[5];
    const float* mb2  = (const float*)d_in[6];
    const float* inw  = (const float*)d_in[7];
    const float* cw   = (const float*)d_in[8];
    const float* cb   = (const float*)d_in[9];
    const float* xpw  = (const float*)d_in[10];
    const float* dtw  = (const float*)d_in[11];
    const float* dtb  = (const float*)d_in[12];
    const float* alog = (const float*)d_in[13];
    const float* Dp   = (const float*)d_in[14];
    const float* outw = (const float*)d_in[15];
    float* out = (float*)d_out;

    // ws: 32.7 MB total
    char* ws = (char*)d_ws;
    unsigned short* xzb = (unsigned short*)(ws);            // xz_T [1536][8192] bf16
    float* BCb = (float*)(ws + 25165824);                   // BC_T [32][8192] f32
    float* xg  = (float*)(ws + 26214400);                   // 8192*4
    int*  vert = (int*)(ws + 26247168);                     // 8*4
    unsigned short* G = (unsigned short*)(ws + 26248192);   // [8][NCH][768][16] bf16 = 3,145,728
    float* sumd = (float*)(ws + 29393920);                  // [8][NCH][768] f32 = 393,216
    unsigned short* inwT  = (unsigned short*)(ws + 29787136);  // [1536][384] bf16
    unsigned short* dtwT  = (unsigned short*)(ws + 30966784);  // [768][768]  bf16
    unsigned short* outwT = (unsigned short*)(ws + 32146432);  // [384][768]  bf16 (ends 32,736,256)

    unsigned short* xnb = (unsigned short*)d_out;  // d_out: xn(bf16) -> xc_T(bf16) -> out(f32)
    unsigned short* xcb = (unsigned short*)d_out;

    k_ln<<<2048, 256, 0, stream>>>(x, ln_g, ln_b, xnb, xg);
    k_dir<<<8, 256, 0, stream>>>(xg, mw1, mb1, mw2, mb2, vert);
    k_wt<<<576, 256, 0, stream>>>(inw, inwT, 384, 1536);
    k_wt<<<576, 256, 0, stream>>>(dtw, dtwT, 768, 768);
    k_wt<<<288, 256, 0, stream>>>(outw, outwT, 768, 384);
    // xz_T = (gather(xn) @ in_proj)^T
    k_mfma<0><<<12 * 64, 256, 0, stream>>>(inwT, xnb, xzb, nullptr, nullptr, vert);
    k_conv<<<1536, 256, 0, stream>>>(xzb, cw, cb, xcb);
    k_xproj<<<128, 256, 0, stream>>>(xcb, xpw, BCb);
    // delta_T = softplus(xc @ dt_w + dt_b)^T  (over xz_T ch<768)
    k_mfma<1><<<6 * 64, 256, 0, stream>>>(dtwT, xcb, xzb, dtb, nullptr, nullptr);
    k_scan1<<<8 * NCH * 48, 256, 0, stream>>>(xzb, xcb, BCb, alog, G, sumd);
    k_scan2<<<8 * 48, 256, 0, stream>>>(G, sumd, alog);
    k_scan3<<<8 * NCH * 48, 256, 0, stream>>>(xzb, xcb, BCb, alog, Dp, G);
    // out = x + y @ out_proj  (y read transposed from xz_T ch<768)
    k_mfma<2><<<3 * 64, 256, 0, stream>>>(xzb, outwT, out, nullptr, x, nullptr);
}

// Round 8
// 217.539 us; speedup vs baseline: 3.0304x; 1.4103x over previous
//
#include <hip/hip_runtime.h>
#include <hip/hip_bf16.h>
#include <math.h>

#define NPOS 8192   // B*H*W = 8*32*32
#define DIMC 384
#define DIN 768
#define DST 16
#define CHUNK 32
#define NCH 32      // 1024 / CHUNK

typedef unsigned int uint;
typedef __attribute__((ext_vector_type(8))) short bf16x8;
typedef __attribute__((ext_vector_type(4))) float f32x4;

__device__ __forceinline__ float b2f(unsigned short u) {
    return __uint_as_float(((unsigned int)u) << 16);
}
// 1-instruction packed f32->bf16 (RNE)
__device__ __forceinline__ uint cvt_pk(float lo, float hi) {
    uint r;
    asm("v_cvt_pk_bf16_f32 %0, %1, %2" : "=v"(r) : "v"(lo), "v"(hi));
    return r;
}
__device__ __forceinline__ unsigned short f2b1(float f) {
    return (unsigned short)cvt_pk(f, f);
}
// fast reciprocal (~1ulp, fine for 0.099 tolerance)
__device__ __forceinline__ float frcp(float x) {
    float r;
    asm("v_rcp_f32 %0, %1" : "=v"(r) : "v"(x));
    return r;
}
__device__ __forceinline__ void ld_bf8(const unsigned short* p, float* o) {
    uint4 u = *(const uint4*)p;
    o[0] = b2f((unsigned short)(u.x & 0xffff));
    o[1] = b2f((unsigned short)(u.x >> 16));
    o[2] = b2f((unsigned short)(u.y & 0xffff));
    o[3] = b2f((unsigned short)(u.y >> 16));
    o[4] = b2f((unsigned short)(u.z & 0xffff));
    o[5] = b2f((unsigned short)(u.z >> 16));
    o[6] = b2f((unsigned short)(u.w & 0xffff));
    o[7] = b2f((unsigned short)(u.w >> 16));
}
__device__ __forceinline__ uint4 pack_bf8(const float* o) {
    uint4 p;
    p.x = cvt_pk(o[0], o[1]);
    p.y = cvt_pk(o[2], o[3]);
    p.z = cvt_pk(o[4], o[5]);
    p.w = cvt_pk(o[6], o[7]);
    return p;
}

// ---------------------------------------------------------------- LayerNorm -> bf16 xn
__global__ __launch_bounds__(256) void k_ln(const float* __restrict__ x,
        const float* __restrict__ g, const float* __restrict__ bta,
        unsigned short* __restrict__ xnb, float* __restrict__ xg) {
    int wid = blockIdx.x * 4 + (threadIdx.x >> 6);
    int lane = threadIdx.x & 63;
    const float* xr = x + (size_t)wid * DIMC;
    float v[6];
    float s = 0.f, ss = 0.f;
#pragma unroll
    for (int i = 0; i < 6; i++) {
        v[i] = xr[lane + i * 64];
        s += v[i]; ss += v[i] * v[i];
    }
#pragma unroll
    for (int m = 32; m; m >>= 1) { s += __shfl_xor(s, m); ss += __shfl_xor(ss, m); }
    float mu = s * (1.f / DIMC);
    float var = ss * (1.f / DIMC) - mu * mu;
    float rstd = rsqrtf(var + 1e-5f);
    unsigned short* xnr = xnb + (size_t)wid * DIMC;
    float sn = 0.f;
#pragma unroll
    for (int i = 0; i < 6; i++) {
        int c = lane + i * 64;
        float o = (v[i] - mu) * rstd * g[c] + bta[c];
        xnr[c] = f2b1(o);
        sn += o;
    }
#pragma unroll
    for (int m = 32; m; m >>= 1) sn += __shfl_xor(sn, m);
    if (lane == 0) xg[wid] = sn * (1.f / DIMC);
}

// ---------------------------------------------------------------- direction
__global__ __launch_bounds__(256) void k_dir(const float* __restrict__ xg,
        const float* __restrict__ w1, const float* __restrict__ b1,
        const float* __restrict__ w2, const float* __restrict__ b2,
        int* __restrict__ vert) {
    __shared__ float sg[32][32];
    __shared__ float red[4][4];
    int b = blockIdx.x;
    int tid = threadIdx.x;
    for (int i = tid; i < 1024; i += 256) sg[i >> 5][i & 31] = xg[b * 1024 + i];
    __syncthreads();
    float ph = 0, pv = 0, pd = 0, pa = 0;
    const float iks = 1.f / 1.0625f;   // kernel_scale = 34/32 (antialias)
    for (int p = tid; p < 1024; p += 256) {
        int y = p >> 5, xq = p & 31;
        int xl = (xq >= 1) ? xq - 1 : 1;
        int xr2 = (xq <= 30) ? xq + 1 : 30;
        float sf = (y + 0.5f) * 1.0625f - 0.5f;
        int jlo = (int)ceilf(sf - 1.0625f); if (jlo < 0) jlo = 0;
        int jhi = (int)floorf(sf + 1.0625f); if (jhi > 33) jhi = 33;
        float acc = 0.f, wsum = 0.f;
        for (int j = jlo; j <= jhi; j++) {
            float wgt = 1.f - fabsf(sf - j) * iks;
            if (wgt <= 0.f) continue;
            int ry = (j >= 1) ? ((j <= 32) ? j - 1 : 30) : 1;
            acc += wgt * fabsf(sg[ry][xr2] - sg[ry][xl]);
            wsum += wgt;
        }
        float ghr = acc / wsum;
        int yu = (y >= 1) ? y - 1 : 1;
        int yd = (y <= 30) ? y + 1 : 30;
        float sfx = (xq + 0.5f) * 1.0625f - 0.5f;
        int ilo = (int)ceilf(sfx - 1.0625f); if (ilo < 0) ilo = 0;
        int ihi = (int)floorf(sfx + 1.0625f); if (ihi > 33) ihi = 33;
        float accv = 0.f, wsv = 0.f;
        for (int i = ilo; i <= ihi; i++) {
            float wgt = 1.f - fabsf(sfx - i) * iks;
            if (wgt <= 0.f) continue;
            int rx = (i >= 1) ? ((i <= 32) ? i - 1 : 30) : 1;
            accv += wgt * fabsf(sg[yd][rx] - sg[yu][rx]);
            wsv += wgt;
        }
        float gvr = accv / wsv;
        float gd = (ghr + gvr) * 0.5f;
        float ga = fabsf(ghr - gvr);
        float cw = ((y == 0 || y == 31) ? 2.f : 3.f) * ((xq == 0 || xq == 31) ? 2.f : 3.f);
        ph += ghr * cw; pv += gvr * cw; pd += gd * cw; pa += ga * cw;
    }
#pragma unroll
    for (int m = 32; m; m >>= 1) {
        ph += __shfl_xor(ph, m); pv += __shfl_xor(pv, m);
        pd += __shfl_xor(pd, m); pa += __shfl_xor(pa, m);
    }
    int wv = tid >> 6;
    if ((tid & 63) == 0) { red[wv][0] = ph; red[wv][1] = pv; red[wv][2] = pd; red[wv][3] = pa; }
    __syncthreads();
    if (tid == 0) {
        float sc[4];
        for (int k = 0; k < 4; k++)
            sc[k] = (red[0][k] + red[1][k] + red[2][k] + red[3][k]) * (1.f / 9216.f);
        float hdn[32];
        for (int j = 0; j < 32; j++) {
            float a = b1[j];
            for (int i = 0; i < 4; i++) a += sc[i] * w1[i * 32 + j];
            hdn[j] = a > 0.f ? a : 0.f;
        }
        float best = -1e30f; int bi = 0;
        for (int k = 0; k < 4; k++) {
            float a = b2[k];
            for (int j = 0; j < 32; j++) a += hdn[j] * w2[j * 4 + k];
            if (a > best) { best = a; bi = k; }
        }
        vert[b] = (bi == 1) ? 1 : 0;
    }
}

// ---------------------------------------------------------------- weight prep: W[K][N] f32 -> WT[N][K] bf16
__global__ __launch_bounds__(256) void k_wt(const float* __restrict__ W,
        unsigned short* __restrict__ WT, int K, int N) {
    __shared__ float t[32][33];
    int nb = N >> 5;
    int n0 = (blockIdx.x % nb) << 5, k0 = (blockIdx.x / nb) << 5;
    int i = threadIdx.x;
    int kr = i >> 3, n4 = (i & 7) << 2;
    float4 v = *(const float4*)(W + (size_t)(k0 + kr) * N + n0 + n4);
    t[kr][n4 + 0] = v.x; t[kr][n4 + 1] = v.y; t[kr][n4 + 2] = v.z; t[kr][n4 + 3] = v.w;
    __syncthreads();
    int nr = i >> 3, k4 = (i & 7) << 2;
    ushort4 o;
    o.x = f2b1(t[k4 + 0][nr]); o.y = f2b1(t[k4 + 1][nr]);
    o.z = f2b1(t[k4 + 2][nr]); o.w = f2b1(t[k4 + 3][nr]);
    *(ushort4*)(WT + (size_t)(n0 + nr) * K + k0 + k4) = o;
}

// ---------------------------------------------------------------- MFMA GEMM
template <bool SWZ>
__device__ __forceinline__ bf16x8 frag_rd(const unsigned short* L, int rr, int lg) {
    int ch = lg << 3;
    if constexpr (SWZ) ch ^= ((rr >> 4) & 3) << 3;
    return *(const bf16x8*)&L[rr * 40 + ch];
}

template <int MODE>
__global__ __launch_bounds__(256) void k_mfma(
        const unsigned short* __restrict__ op1,
        const unsigned short* __restrict__ op2,
        void* __restrict__ outp,
        const float* __restrict__ bias,
        const float* __restrict__ resid,
        const int* __restrict__ vert) {
    constexpr int K = (MODE == 0) ? 384 : 768;
    constexpr int NK = K / 32;
    constexpr int NBN = (MODE == 0) ? 12 : (MODE == 1 ? 6 : 3);
    __shared__ unsigned short lds[2][2][128 * 40];
    int tid = threadIdx.x;
    int n0 = (blockIdx.x % NBN) << 7;
    int m0 = (blockIdx.x / NBN) << 7;

    int drow = tid >> 1, dkh = (tid & 1) << 4;      // direct staging coords
    int td = tid >> 3, ttof = (tid & 7) << 4;       // transposed staging coords
    int tsw = td ^ ((tid & 3) << 3);                // swizzled d slot (const/thread)

    size_t g1row = 0, g2row = 0;
    if constexpr (MODE == 0) {
        g1row = (size_t)(n0 + drow) * 384;
        int m = m0 + drow;
        int b = m >> 10, l = m & 1023;
        int src = vert[b] ? (((l & 31) << 5) | (l >> 5)) : l;
        g2row = ((size_t)(b << 10) + src) * 384;
    } else if constexpr (MODE == 1) {
        g1row = (size_t)(n0 + drow) * 768;
    } else {
        g2row = (size_t)(n0 + drow) * 768;
    }

    f32x4 acc[4][4];
    f32x4 zero = {0.f, 0.f, 0.f, 0.f};
#pragma unroll
    for (int i = 0; i < 4; i++)
#pragma unroll
        for (int j = 0; j < 4; j++) acc[i][j] = zero;

    uint4 s1a, s1b, s2a, s2b;

#define LOAD1(k0_)                                                              \
    { if constexpr (MODE == 2) {                                                \
          const unsigned short* p = op1 + (size_t)((k0_) + td) * 8192 + m0 + ttof; \
          s1a = *(const uint4*)p; s1b = *(const uint4*)(p + 8);                 \
      } else {                                                                  \
          const unsigned short* p = op1 + g1row + (k0_) + dkh;                  \
          s1a = *(const uint4*)p; s1b = *(const uint4*)(p + 8);                 \
      } }
#define LOAD2(k0_)                                                              \
    { if constexpr (MODE == 1) {                                                \
          const unsigned short* p = op2 + (size_t)((k0_) + td) * 8192 + m0 + ttof; \
          s2a = *(const uint4*)p; s2b = *(const uint4*)(p + 8);                 \
      } else {                                                                  \
          const unsigned short* p = op2 + g2row + (k0_) + dkh;                  \
          s2a = *(const uint4*)p; s2b = *(const uint4*)(p + 8);                 \
      } }
#define WRITE1(buf_)                                                            \
    { unsigned short* L = &lds[buf_][0][0];                                     \
      if constexpr (MODE == 2) {                                                \
          const unsigned short* va = (const unsigned short*)&s1a;               \
          const unsigned short* vb = (const unsigned short*)&s1b;               \
          _Pragma("unroll") for (int j = 0; j < 8; j++) L[(ttof + j) * 40 + tsw] = va[j]; \
          _Pragma("unroll") for (int j = 0; j < 8; j++) L[(ttof + 8 + j) * 40 + tsw] = vb[j]; \
      } else {                                                                  \
          *(uint4*)&L[drow * 40 + dkh] = s1a;                                   \
          *(uint4*)&L[drow * 40 + dkh + 8] = s1b;                               \
      } }
#define WRITE2(buf_)                                                            \
    { unsigned short* L = &lds[buf_][1][0];                                     \
      if constexpr (MODE == 1) {                                                \
          const unsigned short* va = (const unsigned short*)&s2a;               \
          const unsigned short* vb = (const unsigned short*)&s2b;               \
          _Pragma("unroll") for (int j = 0; j < 8; j++) L[(ttof + j) * 40 + tsw] = va[j]; \
          _Pragma("unroll") for (int j = 0; j < 8; j++) L[(ttof + 8 + j) * 40 + tsw] = vb[j]; \
      } else {                                                                  \
          *(uint4*)&L[drow * 40 + dkh] = s2a;                                   \
          *(uint4*)&L[drow * 40 + dkh + 8] = s2b;                               \
      } }

    int wid = tid >> 6, lane = tid & 63;
    int lr = lane & 15, lg = lane >> 4;
    int o1b = (wid >> 1) << 6;   // op1-row 64-block within tile
    int o2b = (wid & 1) << 6;    // op2-row 64-block within tile

    LOAD1(0) LOAD2(0)
    WRITE1(0) WRITE2(0)
    int cur = 0;
    for (int ks = 0; ks < NK; ks++) {
        int kn = (ks + 1) << 5;
        if (ks + 1 < NK) { LOAD1(kn) LOAD2(kn) }
        __syncthreads();
        const unsigned short* L1 = &lds[cur][0][0];
        const unsigned short* L2 = &lds[cur][1][0];
        bf16x8 f1[4], f2[4];
#pragma unroll
        for (int f = 0; f < 4; f++) f1[f] = frag_rd<(MODE == 2)>(L1, o1b + f * 16 + lr, lg);
#pragma unroll
        for (int f = 0; f < 4; f++) f2[f] = frag_rd<(MODE == 1)>(L2, o2b + f * 16 + lr, lg);
#pragma unroll
        for (int i = 0; i < 4; i++)
#pragma unroll
            for (int j = 0; j < 4; j++)
                acc[i][j] = __builtin_amdgcn_mfma_f32_16x16x32_bf16(f1[i], f2[j], acc[i][j], 0, 0, 0);
        if (ks + 1 < NK) { WRITE1(cur ^ 1) WRITE2(cur ^ 1) }
        cur ^= 1;
    }

    if constexpr (MODE <= 1) {
        unsigned short* CT = (unsigned short*)outp;
#pragma unroll
        for (int i = 0; i < 4; i++) {
            int nb_ = n0 + o1b + i * 16 + lg * 4;
#pragma unroll
            for (int j = 0; j < 4; j++) {
                int mb_ = m0 + o2b + j * 16 + lr;
#pragma unroll
                for (int r = 0; r < 4; r++) {
                    int n = nb_ + r;
                    float v = acc[i][j][r];
                    if constexpr (MODE == 1) {
                        v += bias[n];
                        v = fmaxf(v, 0.f) + __logf(1.f + __expf(-fabsf(v)));   // softplus
                    }
                    CT[(size_t)n * 8192 + mb_] = f2b1(v);
                }
            }
        }
    } else {
        float* C = (float*)outp;
#pragma unroll
        for (int i = 0; i < 4; i++) {
            int mb_ = m0 + o1b + i * 16 + lg * 4;
#pragma unroll
            for (int j = 0; j < 4; j++) {
                int n = n0 + o2b + j * 16 + lr;
#pragma unroll
                for (int r = 0; r < 4; r++) {
                    int m = mb_ + r;
                    C[(size_t)m * 384 + n] = acc[i][j][r] + resid[(size_t)m * 384 + n];
                }
            }
        }
    }
#undef LOAD1
#undef LOAD2
#undef WRITE1
#undef WRITE2
}

// ---------------------------------------------------------------- depthwise conv3 + silu
__global__ __launch_bounds__(256) void k_conv(const unsigned short* __restrict__ xzb,
        const float* __restrict__ cw, const float* __restrict__ cb,
        unsigned short* __restrict__ xcb) {
    int gc = blockIdx.x * 256 + threadIdx.x;   // 768 * 512
    int d = gc >> 9;
    int t0 = (gc & 511) << 4;
    const unsigned short* xr = xzb + (size_t)d * 8192;
    float xx[16];
    ld_bf8(xr + t0, xx);
    ld_bf8(xr + t0 + 8, xx + 8);
    int l0 = t0 & 1023;
    float xprev = (l0 != 0)    ? b2f(xr[t0 - 1])  : 0.f;
    float xnext = (l0 != 1008) ? b2f(xr[t0 + 16]) : 0.f;
    float w0 = cw[d * 3], w1 = cw[d * 3 + 1], w2 = cw[d * 3 + 2], bb = cb[d];
    float o[16];
#pragma unroll
    for (int j = 0; j < 16; j++) {
        float v = bb + w1 * xx[j];
        v += w0 * ((j == 0) ? xprev : xx[j - 1]);
        v += w2 * ((j == 15) ? xnext : xx[j + 1]);
        o[j] = v * frcp(1.f + __expf(-v));
    }
    *(uint4*)(xcb + (size_t)d * 8192 + t0)     = pack_bf8(o);
    *(uint4*)(xcb + (size_t)d * 8192 + t0 + 8) = pack_bf8(o + 8);
}

// ---------------------------------------------------------------- x_proj
__global__ __launch_bounds__(256) void k_xproj(const unsigned short* __restrict__ xcb,
        const float* __restrict__ xw, float* __restrict__ BC) {
    __shared__ unsigned short sx[32][64];
    int r0 = blockIdx.x * 64;
    int tid = threadIdx.x;
    int n = tid & 31, rg = tid >> 5;
    float acc[8] = {};
    for (int k0 = 0; k0 < 768; k0 += 32) {
        int kk = tid >> 3, r8 = (tid & 7) << 3;
        *(uint4*)&sx[kk][r8] = *(const uint4*)(xcb + (size_t)(k0 + kk) * 8192 + r0 + r8);
        __syncthreads();
#pragma unroll 8
        for (int k2 = 0; k2 < 32; k2++) {
            float w = xw[(k0 + k2) * 32 + n];
            float xb[8];
            ld_bf8(&sx[k2][rg << 3], xb);
#pragma unroll
            for (int j = 0; j < 8; j++) acc[j] = fmaf(xb[j], w, acc[j]);
        }
        __syncthreads();
    }
    float* dst = BC + (size_t)n * 8192 + r0 + (rg << 3);
    *(float4*)dst       = make_float4(acc[0], acc[1], acc[2], acc[3]);
    *(float4*)(dst + 4) = make_float4(acc[4], acc[5], acc[6], acc[7]);
}

// ---------------------------------------------------------------- chunked scan (n-in-thread)
// Pass 1: thread owns d; local chain from h=0 -> G[b][c][d][0..15] bf16, sumd.
__global__ __launch_bounds__(256) void k_scan1(const unsigned short* __restrict__ xzb,
        const unsigned short* __restrict__ xcb, const float* __restrict__ BC,
        const float* __restrict__ A_log,
        unsigned short* __restrict__ G, float* __restrict__ sumd) {
    __shared__ float sB[CHUNK][16];
    int blk = blockIdx.x;              // 8b * NCH * 3dg
    int dg = blk % 3;
    int c  = (blk / 3) % NCH;
    int b  = blk / (3 * NCH);
    int tid = threadIdx.x;
    int d = dg * 256 + tid;
    size_t r0 = (size_t)b * 1024 + c * CHUNK;
    for (int i = tid; i < CHUNK * 16; i += 256) {
        int t = i & (CHUNK - 1), n = i / CHUNK;
        sB[t][n] = BC[(size_t)n * 8192 + r0 + t];
    }
    __syncthreads();
    float Av[16];
#pragma unroll
    for (int q = 0; q < 4; q++) {
        float4 a4 = *(const float4*)(A_log + d * 16 + q * 4);
        Av[q * 4 + 0] = -__expf(a4.x);
        Av[q * 4 + 1] = -__expf(a4.y);
        Av[q * 4 + 2] = -__expf(a4.z);
        Av[q * 4 + 3] = -__expf(a4.w);
    }
    const unsigned short* dptr = xzb + (size_t)d * 8192 + r0;
    const unsigned short* xptr = xcb + (size_t)d * 8192 + r0;
    float h[16] = {};
    float sd = 0.f;
    for (int t0 = 0; t0 < CHUNK; t0 += 8) {
        float dv[8], xv[8];
        ld_bf8(dptr + t0, dv);
        ld_bf8(xptr + t0, xv);
#pragma unroll
        for (int j = 0; j < 8; j++) {
            float dx = dv[j] * xv[j];
            sd += dv[j];
            const float* Bt = &sB[t0 + j][0];
#pragma unroll
            for (int n = 0; n < 16; n++) {
                float dA = __expf(dv[j] * Av[n]);
                h[n] = fmaf(dA, h[n], dx * Bt[n]);
            }
        }
    }
    unsigned short* gp = G + (((size_t)(b * NCH + c)) * 768 + d) * 16;
    *(uint4*)gp       = pack_bf8(h);
    *(uint4*)(gp + 8) = pack_bf8(h + 8);
    sumd[(size_t)(b * NCH + c) * 768 + d] = sd;
}

// Pass 2: sequential carry across chunks; G := carry-IN state of chunk c
__global__ __launch_bounds__(256) void k_scan2(unsigned short* __restrict__ G,
        const float* __restrict__ sumd, const float* __restrict__ A_log) {
    int blk = blockIdx.x;              // 8b * 48dg
    int dg = blk % 48, b = blk / 48;
    int tid = threadIdx.x;
    int dl = tid >> 4, n = tid & 15;
    int d = dg * 16 + dl;
    float Av = -__expf(A_log[d * 16 + n]);
    float H = 0.f;
#pragma unroll 8
    for (int c = 0; c < NCH; c++) {
        size_t gi = (((size_t)(b * NCH + c)) * 768 + d) * 16 + n;
        float Gv = b2f(G[gi]);
        float P = __expf(Av * sumd[(size_t)(b * NCH + c) * 768 + d]);
        G[gi] = f2b1(H);               // carry-in for chunk c
        H = fmaf(P, H, Gv);
    }
}

// Pass 3: thread owns d; seeded chain; y overwrites delta in-place.
__global__ __launch_bounds__(256) void k_scan3(unsigned short* xzb,
        const unsigned short* __restrict__ xcb, const float* __restrict__ BC,
        const float* __restrict__ A_log, const float* __restrict__ Dp,
        const unsigned short* __restrict__ G) {
    __shared__ float sB[CHUNK][16];
    __shared__ float sC[CHUNK][16];
    int blk = blockIdx.x;              // 8b * NCH * 3dg
    int dg = blk % 3;
    int c  = (blk / 3) % NCH;
    int b  = blk / (3 * NCH);
    int tid = threadIdx.x;
    int d = dg * 256 + tid;
    size_t r0 = (size_t)b * 1024 + c * CHUNK;
    for (int i = tid; i < CHUNK * 16; i += 256) {
        int t = i & (CHUNK - 1), n = i / CHUNK;
        sB[t][n] = BC[(size_t)n * 8192 + r0 + t];
        sC[t][n] = BC[(size_t)(16 + n) * 8192 + r0 + t];
    }
    __syncthreads();
    float Av[16];
#pragma unroll
    for (int q = 0; q < 4; q++) {
        float4 a4 = *(const float4*)(A_log + d * 16 + q * 4);
        Av[q * 4 + 0] = -__expf(a4.x);
        Av[q * 4 + 1] = -__expf(a4.y);
        Av[q * 4 + 2] = -__expf(a4.z);
        Av[q * 4 + 3] = -__expf(a4.w);
    }
    float Dv = Dp[d];
    float h[16];
    const unsigned short* gp = G + (((size_t)(b * NCH + c)) * 768 + d) * 16;
    ld_bf8(gp, h);
    ld_bf8(gp + 8, h + 8);
    unsigned short* dptr       = xzb + (size_t)d * 8192 + r0;          // delta -> y
    const unsigned short* zptr = xzb + (size_t)(768 + d) * 8192 + r0;  // z
    const unsigned short* xptr = xcb + (size_t)d * 8192 + r0;          // xc
    for (int t0 = 0; t0 < CHUNK; t0 += 8) {
        float dv[8], xv[8], zv[8], yr[8];
        ld_bf8(dptr + t0, dv);
        ld_bf8(xptr + t0, xv);
        ld_bf8(zptr + t0, zv);
#pragma unroll
        for (int j = 0; j < 8; j++) {
            float dx = dv[j] * xv[j];
            const float* Bt = &sB[t0 + j][0];
            const float* Ct = &sC[t0 + j][0];
            float p0 = 0.f, p1 = 0.f, p2 = 0.f, p3 = 0.f;
#pragma unroll
            for (int n = 0; n < 16; n += 4) {
                float dA0 = __expf(dv[j] * Av[n + 0]);
                float dA1 = __expf(dv[j] * Av[n + 1]);
                float dA2 = __expf(dv[j] * Av[n + 2]);
                float dA3 = __expf(dv[j] * Av[n + 3]);
                h[n + 0] = fmaf(dA0, h[n + 0], dx * Bt[n + 0]);
                h[n + 1] = fmaf(dA1, h[n + 1], dx * Bt[n + 1]);
                h[n + 2] = fmaf(dA2, h[n + 2], dx * Bt[n + 2]);
                h[n + 3] = fmaf(dA3, h[n + 3], dx * Bt[n + 3]);
                p0 = fmaf(h[n + 0], Ct[n + 0], p0);
                p1 = fmaf(h[n + 1], Ct[n + 1], p1);
                p2 = fmaf(h[n + 2], Ct[n + 2], p2);
                p3 = fmaf(h[n + 3], Ct[n + 3], p3);
            }
            float p = (p0 + p1) + (p2 + p3);
            float zz = zv[j];
            float sig = frcp(1.f + __expf(-zz));
            yr[j] = fmaf(Dv, xv[j], p) * zz * sig;
        }
        *(uint4*)(dptr + t0) = pack_bf8(yr);
    }
}

// ---------------------------------------------------------------- launch
extern "C" void kernel_launch(void* const* d_in, const int* in_sizes, int n_in,
                              void* d_out, int out_size, void* d_ws, size_t ws_size,
                              hipStream_t stream) {
    const float* x    = (const float*)d_in[0];
    const float* ln_g = (const float*)d_in[1];
    const float* ln_b = (const float*)d_in[2];
    const float* mw1  = (const float*)d_in[3];
    const float* mb1  = (const float*)d_in[4];
    const float* mw2  = (const float*)d_in[5];
    const float* mb2  = (const float*)d_in[6];
    const float* inw  = (const float*)d_in[7];
    const float* cw   = (const float*)d_in[8];
    const float* cb   = (const float*)d_in[9];
    const float* xpw  = (const float*)d_in[10];
    const float* dtw  = (const float*)d_in[11];
    const float* dtb  = (const float*)d_in[12];
    const float* alog = (const float*)d_in[13];
    const float* Dp   = (const float*)d_in[14];
    const float* outw = (const float*)d_in[15];
    float* out = (float*)d_out;

    // ws: 36.3 MB total (ws_size deduced ~48 MiB from round-2 overflow; margin kept)
    char* ws = (char*)d_ws;
    unsigned short* xzb = (unsigned short*)(ws);            // xz_T [1536][8192] bf16
    float* BCb = (float*)(ws + 25165824);                   // BC_T [32][8192] f32
    float* xg  = (float*)(ws + 26214400);                   // 8192*4
    int*  vert = (int*)(ws + 26247168);                     // 8*4 (+pad)
    unsigned short* G = (unsigned short*)(ws + 26248192);   // [8][NCH][768][16] bf16 = 6,291,456
    float* sumd = (float*)(ws + 32539648);                  // [8][NCH][768] f32 = 786,432
    unsigned short* inwT  = (unsigned short*)(ws + 33326080);  // [1536][384] bf16
    unsigned short* dtwT  = (unsigned short*)(ws + 34505728);  // [768][768]  bf16
    unsigned short* outwT = (unsigned short*)(ws + 35685376);  // [384][768]  bf16 (ends 36,275,200)

    unsigned short* xnb = (unsigned short*)d_out;  // d_out: xn(bf16) -> xc_T(bf16) -> out(f32)
    unsigned short* xcb = (unsigned short*)d_out;

    k_ln<<<2048, 256, 0, stream>>>(x, ln_g, ln_b, xnb, xg);
    k_dir<<<8, 256, 0, stream>>>(xg, mw1, mb1, mw2, mb2, vert);
    k_wt<<<576, 256, 0, stream>>>(inw, inwT, 384, 1536);
    k_wt<<<576, 256, 0, stream>>>(dtw, dtwT, 768, 768);
    k_wt<<<288, 256, 0, stream>>>(outw, outwT, 768, 384);
    // xz_T = (gather(xn) @ in_proj)^T
    k_mfma<0><<<12 * 64, 256, 0, stream>>>(inwT, xnb, xzb, nullptr, nullptr, vert);
    k_conv<<<1536, 256, 0, stream>>>(xzb, cw, cb, xcb);
    k_xproj<<<128, 256, 0, stream>>>(xcb, xpw, BCb);
    // delta_T = softplus(xc @ dt_w + dt_b)^T  (over xz_T ch<768)
    k_mfma<1><<<6 * 64, 256, 0, stream>>>(dtwT, xcb, xzb, dtb, nullptr, nullptr);
    k_scan1<<<8 * NCH * 3, 256, 0, stream>>>(xzb, xcb, BCb, alog, G, sumd);
    k_scan2<<<8 * 48, 256, 0, stream>>>(G, sumd, alog);
    k_scan3<<<8 * NCH * 3, 256, 0, stream>>>(xzb, xcb, BCb, alog, Dp, G);
    // out = x + y @ out_proj  (y read transposed from xz_T ch<768)
    k_mfma<2><<<3 * 64, 256, 0, stream>>>(xzb, outwT, out, nullptr, x, nullptr);
}